// Round 1
// baseline (2001.411 us; speedup 1.0000x reference)
//
#include <hip/hip_runtime.h>
#include <hip/hip_bf16.h>

#define D_MODEL 1024
#define N_TOK   4096
#define HEADS   16
#define HEAD_DIM 64
#define FF_DIM  4096
#define SEQ_L   2048

// ---------------------------------------------------------------------------
// GEMM: C[M,N] = A[M,K] @ W[K,N] + bias, optional ReLU.
// 64x64 block tile, BK=16, 256 threads (16x16), 4x4 microtile, float4 LDS.
// ---------------------------------------------------------------------------
template<int RELU>
__global__ __launch_bounds__(256)
void sgemm_bias(const float* __restrict__ A, const float* __restrict__ W,
                const float* __restrict__ bias, float* __restrict__ C,
                int M, int N, int K)
{
    __shared__ float As[16][64];   // [k][m]  (A staged transposed)
    __shared__ float Bs[16][64];   // [k][n]

    const int tid = threadIdx.x;
    const int tx = tid & 15, ty = tid >> 4;
    const int r0 = blockIdx.y * 64, c0 = blockIdx.x * 64;

    const int ar = tid >> 2;          // A-tile row 0..63
    const int ak = (tid & 3) * 4;     // A-tile k chunk
    const int bk = tid >> 4;          // B-tile k 0..15
    const int bc = (tid & 15) * 4;    // B-tile col chunk

    float acc[4][4] = {};

    for (int k0 = 0; k0 < K; k0 += 16) {
        __syncthreads();
        float4 va = *(const float4*)(A + (size_t)(r0 + ar) * K + k0 + ak);
        As[ak + 0][ar] = va.x;
        As[ak + 1][ar] = va.y;
        As[ak + 2][ar] = va.z;
        As[ak + 3][ar] = va.w;
        *(float4*)&Bs[bk][bc] = *(const float4*)(W + (size_t)(k0 + bk) * N + c0 + bc);
        __syncthreads();
#pragma unroll
        for (int k = 0; k < 16; ++k) {
            float4 a4 = *(const float4*)&As[k][ty * 4];
            float4 b4 = *(const float4*)&Bs[k][tx * 4];
            float av[4] = {a4.x, a4.y, a4.z, a4.w};
            float bv[4] = {b4.x, b4.y, b4.z, b4.w};
#pragma unroll
            for (int i = 0; i < 4; ++i)
#pragma unroll
                for (int j = 0; j < 4; ++j)
                    acc[i][j] += av[i] * bv[j];
        }
    }

#pragma unroll
    for (int i = 0; i < 4; ++i) {
        const int r = r0 + ty * 4 + i;
        float4 o;
        float* po = &o.x;
#pragma unroll
        for (int j = 0; j < 4; ++j) {
            const int c = c0 + tx * 4 + j;
            float v = acc[i][j] + bias[c];
            if (RELU) v = fmaxf(v, 0.f);
            po[j] = v;
        }
        *(float4*)(C + (size_t)r * N + c0 + tx * 4) = o;
    }
}

// ---------------------------------------------------------------------------
// Flash attention: one block per (b*H + h, q-tile of 64 rows). 256 threads.
// Scores held in registers (4x4 microtile); online softmax via 16-lane shfl.
// ---------------------------------------------------------------------------
__global__ __launch_bounds__(256)
void attn_flash(const float* __restrict__ q, const float* __restrict__ k,
                const float* __restrict__ v, float* __restrict__ o)
{
    __shared__ float Qt[64][64];   // [d][m], pre-scaled by 1/sqrt(64)
    __shared__ float Kt[64][64];   // [d][s]
    __shared__ float Vs[64][64];   // [s][d]
    __shared__ float Pt[64][68];   // [s][m], padded to 68 for bank spread

    const int tid = threadIdx.x;
    const int bh = blockIdx.y;             // b*HEADS + h
    const int b  = bh >> 4;
    const int h  = bh & 15;
    const int ho = h * HEAD_DIM;
    const int tb = b * SEQ_L;
    const int q0 = blockIdx.x * 64;

    const int sr = tid >> 2;               // staging row 0..63
    const int sd = (tid & 3) * 16;         // staging col base

    // stage Q (transposed + scaled)
    {
        const float* src = q + (size_t)(tb + q0 + sr) * D_MODEL + ho + sd;
#pragma unroll
        for (int u = 0; u < 4; ++u) {
            float4 t4 = *(const float4*)(src + u * 4);
            Qt[sd + u * 4 + 0][sr] = t4.x * 0.125f;
            Qt[sd + u * 4 + 1][sr] = t4.y * 0.125f;
            Qt[sd + u * 4 + 2][sr] = t4.z * 0.125f;
            Qt[sd + u * 4 + 3][sr] = t4.w * 0.125f;
        }
    }

    const int tx = tid & 15, ty = tid >> 4;

    float m_i[4], l_i[4];
    float oacc[4][4];
#pragma unroll
    for (int i = 0; i < 4; ++i) {
        m_i[i] = -1e30f; l_i[i] = 0.f;
#pragma unroll
        for (int j = 0; j < 4; ++j) oacc[i][j] = 0.f;
    }

    for (int s0 = 0; s0 < SEQ_L; s0 += 64) {
        __syncthreads();   // prev PV done (and Q staged, first iter)
        {
            const float* ksrc = k + (size_t)(tb + s0 + sr) * D_MODEL + ho + sd;
            const float* vsrc = v + (size_t)(tb + s0 + sr) * D_MODEL + ho + sd;
#pragma unroll
            for (int u = 0; u < 4; ++u) {
                float4 t4 = *(const float4*)(ksrc + u * 4);
                Kt[sd + u * 4 + 0][sr] = t4.x;
                Kt[sd + u * 4 + 1][sr] = t4.y;
                Kt[sd + u * 4 + 2][sr] = t4.z;
                Kt[sd + u * 4 + 3][sr] = t4.w;
                *(float4*)&Vs[sr][sd + u * 4] = *(const float4*)(vsrc + u * 4);
            }
        }
        __syncthreads();

        // S = (Q*scale) @ K^T  -> sacc[i][j], rows 4ty+i, cols 4tx+j
        float sacc[4][4] = {};
#pragma unroll 8
        for (int d = 0; d < 64; ++d) {
            float4 a4 = *(const float4*)&Qt[d][ty * 4];
            float4 b4 = *(const float4*)&Kt[d][tx * 4];
            float av[4] = {a4.x, a4.y, a4.z, a4.w};
            float bv[4] = {b4.x, b4.y, b4.z, b4.w};
#pragma unroll
            for (int i = 0; i < 4; ++i)
#pragma unroll
                for (int j = 0; j < 4; ++j)
                    sacc[i][j] += av[i] * bv[j];
        }

        // online softmax per row i (reduce across the 16 tx lanes)
#pragma unroll
        for (int i = 0; i < 4; ++i) {
            float tmax = fmaxf(fmaxf(sacc[i][0], sacc[i][1]),
                               fmaxf(sacc[i][2], sacc[i][3]));
            tmax = fmaxf(tmax, __shfl_xor(tmax, 1));
            tmax = fmaxf(tmax, __shfl_xor(tmax, 2));
            tmax = fmaxf(tmax, __shfl_xor(tmax, 4));
            tmax = fmaxf(tmax, __shfl_xor(tmax, 8));
            float m_new = fmaxf(m_i[i], tmax);
            float corr = __expf(m_i[i] - m_new);
            float rs = 0.f;
#pragma unroll
            for (int j = 0; j < 4; ++j) {
                float p = __expf(sacc[i][j] - m_new);
                sacc[i][j] = p;
                rs += p;
            }
            rs += __shfl_xor(rs, 1);
            rs += __shfl_xor(rs, 2);
            rs += __shfl_xor(rs, 4);
            rs += __shfl_xor(rs, 8);
            l_i[i] = l_i[i] * corr + rs;
            m_i[i] = m_new;
#pragma unroll
            for (int j = 0; j < 4; ++j) oacc[i][j] *= corr;
        }

        // write P transposed: Pt[s][m]
#pragma unroll
        for (int i = 0; i < 4; ++i)
#pragma unroll
            for (int j = 0; j < 4; ++j)
                Pt[4 * tx + j][4 * ty + i] = sacc[i][j];
        __syncthreads();

        // O += P @ V   (a = Pt[s][4ty..], b = Vs[s][4tx..])
#pragma unroll 4
        for (int s = 0; s < 64; ++s) {
            float4 a4 = *(const float4*)&Pt[s][ty * 4];
            float4 b4 = *(const float4*)&Vs[s][tx * 4];
            float av[4] = {a4.x, a4.y, a4.z, a4.w};
            float bv[4] = {b4.x, b4.y, b4.z, b4.w};
#pragma unroll
            for (int i = 0; i < 4; ++i)
#pragma unroll
                for (int j = 0; j < 4; ++j)
                    oacc[i][j] += av[i] * bv[j];
        }
    }

#pragma unroll
    for (int i = 0; i < 4; ++i) {
        const float inv = 1.f / l_i[i];
        float4 o4;
        o4.x = oacc[i][0] * inv; o4.y = oacc[i][1] * inv;
        o4.z = oacc[i][2] * inv; o4.w = oacc[i][3] * inv;
        *(float4*)(o + (size_t)(tb + q0 + 4 * ty + i) * D_MODEL + ho + 4 * tx) = o4;
    }
}

// ---------------------------------------------------------------------------
// Fused residual add + LayerNorm: out = LN(x + y) * g + be.  Block per token.
// ---------------------------------------------------------------------------
__global__ __launch_bounds__(256)
void add_layernorm(const float* __restrict__ x, const float* __restrict__ y,
                   const float* __restrict__ g, const float* __restrict__ be,
                   float* __restrict__ out)
{
    __shared__ float red[4];
    const int t = blockIdx.x;
    const int tid = threadIdx.x;
    const int c = tid * 4;
    const int lane = tid & 63, wid = tid >> 6;

    float4 a = *(const float4*)(x + (size_t)t * D_MODEL + c);
    float4 b = *(const float4*)(y + (size_t)t * D_MODEL + c);
    float s[4] = {a.x + b.x, a.y + b.y, a.z + b.z, a.w + b.w};

    float ps = s[0] + s[1] + s[2] + s[3];
#pragma unroll
    for (int off = 32; off > 0; off >>= 1) ps += __shfl_down(ps, off);
    if (lane == 0) red[wid] = ps;
    __syncthreads();
    const float mean = (red[0] + red[1] + red[2] + red[3]) * (1.f / D_MODEL);
    __syncthreads();

    float pv = 0.f;
#pragma unroll
    for (int u = 0; u < 4; ++u) { float d = s[u] - mean; pv += d * d; }
#pragma unroll
    for (int off = 32; off > 0; off >>= 1) pv += __shfl_down(pv, off);
    if (lane == 0) red[wid] = pv;
    __syncthreads();
    const float var = (red[0] + red[1] + red[2] + red[3]) * (1.f / D_MODEL);
    const float inv = rsqrtf(var + 1e-5f);

    float4 g4 = *(const float4*)(g + c);
    float4 b4 = *(const float4*)(be + c);
    float4 o4;
    o4.x = (s[0] - mean) * inv * g4.x + b4.x;
    o4.y = (s[1] - mean) * inv * g4.y + b4.y;
    o4.z = (s[2] - mean) * inv * g4.z + b4.z;
    o4.w = (s[3] - mean) * inv * g4.w + b4.w;
    *(float4*)(out + (size_t)t * D_MODEL + c) = o4;
}

// ---------------------------------------------------------------------------
extern "C" void kernel_launch(void* const* d_in, const int* in_sizes, int n_in,
                              void* d_out, int out_size, void* d_ws, size_t ws_size,
                              hipStream_t stream)
{
    (void)in_sizes; (void)n_in; (void)out_size; (void)ws_size;

    const float* x   = (const float*)d_in[0];
    const float* Wq  = (const float*)d_in[1];
    const float* bq  = (const float*)d_in[2];
    const float* Wk  = (const float*)d_in[3];
    const float* bk  = (const float*)d_in[4];
    const float* Wv  = (const float*)d_in[5];
    const float* bv  = (const float*)d_in[6];
    const float* Wm  = (const float*)d_in[7];
    const float* bm  = (const float*)d_in[8];
    const float* W1  = (const float*)d_in[9];
    const float* b1  = (const float*)d_in[10];
    const float* W2  = (const float*)d_in[11];
    const float* b2  = (const float*)d_in[12];
    const float* g1  = (const float*)d_in[13];
    const float* be1 = (const float*)d_in[14];
    const float* g2  = (const float*)d_in[15];
    const float* be2 = (const float*)d_in[16];
    float* out = (float*)d_out;
    float* ws  = (float*)d_ws;

    const size_t T = (size_t)N_TOK * D_MODEL;   // 4,194,304 floats
    float* q   = ws;
    float* kk  = ws + T;
    float* vv  = ws + 2 * T;
    float* ao  = ws + 3 * T;
    float* msg = ws + 4 * T;
    float* h   = ws + 5 * T;
    float* f1  = ws;            // reuse q..ao region (4*T floats = FFN activ)

    dim3 blk(256);

    sgemm_bias<0><<<dim3(16, 64), blk, 0, stream>>>(x,  Wq, bq, q,  N_TOK, D_MODEL, D_MODEL);
    sgemm_bias<0><<<dim3(16, 64), blk, 0, stream>>>(x,  Wk, bk, kk, N_TOK, D_MODEL, D_MODEL);
    sgemm_bias<0><<<dim3(16, 64), blk, 0, stream>>>(x,  Wv, bv, vv, N_TOK, D_MODEL, D_MODEL);

    attn_flash<<<dim3(SEQ_L / 64, 2 * HEADS), blk, 0, stream>>>(q, kk, vv, ao);

    sgemm_bias<0><<<dim3(16, 64), blk, 0, stream>>>(ao, Wm, bm, msg, N_TOK, D_MODEL, D_MODEL);
    add_layernorm<<<dim3(N_TOK), blk, 0, stream>>>(x, msg, g1, be1, h);

    sgemm_bias<1><<<dim3(64, 64), blk, 0, stream>>>(h,  W1, b1, f1,  N_TOK, FF_DIM,  D_MODEL);
    sgemm_bias<0><<<dim3(16, 64), blk, 0, stream>>>(f1, W2, b2, msg, N_TOK, D_MODEL, FF_DIM);
    add_layernorm<<<dim3(N_TOK), blk, 0, stream>>>(h, msg, g2, be2, out);
}

// Round 2
// 344.176 us; speedup vs baseline: 5.8151x; 5.8151x over previous
//
#include <hip/hip_runtime.h>

#define D_MODEL 1024
#define N_TOK   4096
#define HEADS   16
#define FF_DIM  4096
#define SEQ_L   2048

typedef unsigned short u16;
typedef __bf16 bf16x8 __attribute__((ext_vector_type(8)));
typedef float  f32x4  __attribute__((ext_vector_type(4)));

#define AS1C(p) ((const __attribute__((address_space(1))) void*)(p))
#define AS3(p)  ((__attribute__((address_space(3))) void*)(p))

__device__ __forceinline__ u16 f2bf(float f) {
    union { float f; unsigned u; } c; c.f = f;
    return (u16)((c.u + 0x7fffu + ((c.u >> 16) & 1u)) >> 16);   // RNE
}
__device__ __forceinline__ float bf2f(u16 b) {
    union { unsigned u; float f; } c; c.u = ((unsigned)b) << 16;
    return c.f;
}

// ---------------------------------------------------------------------------
// bf16 GEMM, C[M,N] = A[M,K] @ Bt[N,K]^T + bias, optional ReLU.
// Tile: BM = MFR*32 rows x 128 cols, BK=64. 4 waves (2x2). MFMA 16x16x32.
// LDS staged via global_load_lds(16B) with pre-swizzled global source
// (chunk ^ (row&7)); ds_read_b128 applies the same XOR -> conflict-free.
// ---------------------------------------------------------------------------
template<int MFR, int RELU, int OUT_BF16>
__global__ __launch_bounds__(256)
void gemm_bt(const u16* __restrict__ A, const u16* __restrict__ Bt,
             const float* __restrict__ bias, void* __restrict__ Cv,
             int M, int N, int K)
{
    constexpr int BM = MFR * 32;
    __shared__ u16 As[BM * 64];
    __shared__ u16 Bs[128 * 64];

    const int tid  = threadIdx.x;
    const int wid  = tid >> 6, lane = tid & 63;
    const int wr   = wid >> 1, wc = wid & 1;
    const int l15  = lane & 15, l16 = lane >> 4;
    const int r0   = blockIdx.y * BM, c0 = blockIdx.x * 128;

    f32x4 acc[MFR][4];
#pragma unroll
    for (int m = 0; m < MFR; ++m)
#pragma unroll
        for (int n = 0; n < 4; ++n) acc[m][n] = (f32x4){0.f, 0.f, 0.f, 0.f};

    for (int k0 = 0; k0 < K; k0 += 64) {
        __syncthreads();
#pragma unroll
        for (int i = 0; i < BM / 32; ++i) {          // A: BM rows x 128B
            const int rb = wid * (BM / 4) + i * 8;
            const int r  = rb + (lane >> 3);
            const int gc = (lane & 7) ^ (r & 7);
            __builtin_amdgcn_global_load_lds(AS1C(A + (size_t)(r0 + r) * K + k0 + gc * 8),
                                             AS3(&As[rb * 64]), 16, 0, 0);
        }
#pragma unroll
        for (int i = 0; i < 4; ++i) {                // B: 128 rows x 128B
            const int rb = wid * 32 + i * 8;
            const int r  = rb + (lane >> 3);
            const int gc = (lane & 7) ^ (r & 7);
            __builtin_amdgcn_global_load_lds(AS1C(Bt + (size_t)(c0 + r) * K + k0 + gc * 8),
                                             AS3(&Bs[rb * 64]), 16, 0, 0);
        }
        __syncthreads();
#pragma unroll
        for (int ks = 0; ks < 2; ++ks) {
            bf16x8 af[MFR], bb[4];
#pragma unroll
            for (int m = 0; m < MFR; ++m) {
                const int row = wr * (MFR * 16) + m * 16 + l15;
                const int ch  = (ks * 4 + l16) ^ (row & 7);
                af[m] = *(const bf16x8*)&As[row * 64 + ch * 8];
            }
#pragma unroll
            for (int n = 0; n < 4; ++n) {
                const int row = wc * 64 + n * 16 + l15;
                const int ch  = (ks * 4 + l16) ^ (row & 7);
                bb[n] = *(const bf16x8*)&Bs[row * 64 + ch * 8];
            }
#pragma unroll
            for (int m = 0; m < MFR; ++m)
#pragma unroll
                for (int n = 0; n < 4; ++n)
                    acc[m][n] = __builtin_amdgcn_mfma_f32_16x16x32_bf16(af[m], bb[n], acc[m][n], 0, 0, 0);
        }
    }

#pragma unroll
    for (int n = 0; n < 4; ++n) {
        const int col = c0 + wc * 64 + n * 16 + l15;
        const float bv = bias[col];
#pragma unroll
        for (int m = 0; m < MFR; ++m) {
#pragma unroll
            for (int r = 0; r < 4; ++r) {
                const size_t row = (size_t)(r0 + wr * (MFR * 16) + m * 16 + l16 * 4 + r);
                float v = acc[m][n][r] + bv;
                if (RELU) v = fmaxf(v, 0.f);
                if (OUT_BF16) ((u16*)Cv)[row * N + col] = f2bf(v);
                else          ((float*)Cv)[row * N + col] = v;
            }
        }
    }
}

// ---------------------------------------------------------------------------
// MFMA flash attention. qkv: [N_TOK][3072] bf16 (q|k|v per token, head-major).
// Block: 256 thr (4 waves), 64 q-rows (16/wave), s-tiles of 64.
// ---------------------------------------------------------------------------
__global__ __launch_bounds__(256)
void attn_mfma(const u16* __restrict__ qkv, u16* __restrict__ ao)
{
    __shared__ u16 Kl[64 * 64];       // [s][d], chunk^(s&7) swizzle
    __shared__ u16 Vt[64 * 64];       // [d][s], chunk^(d&7) swizzle
    __shared__ u16 Pl[4][16 * 64];    // per-wave [q16][s64], chunk^(q&7)

    const int tid = threadIdx.x;
    const int wid = tid >> 6, lane = tid & 63;
    const int l15 = lane & 15, l16 = lane >> 4;
    const int bh  = blockIdx.y, b = bh >> 4, h = bh & 15;
    const int ho  = h * 64;
    const size_t tb = (size_t)b * SEQ_L;
    const int q0  = blockIdx.x * 64;

    const u16* qg = qkv + (tb + q0) * 3072 + ho;
    const u16* kg = qkv + tb * 3072 + 1024 + ho;
    const u16* vg = qkv + tb * 3072 + 2048 + ho;

    bf16x8 qa[2];
#pragma unroll
    for (int ks = 0; ks < 2; ++ks)
        qa[ks] = *(const bf16x8*)(qg + (size_t)(wid * 16 + l15) * 3072 + ks * 32 + l16 * 8);

    f32x4 oacc[4];
    float m_i[4], l_i[4];
#pragma unroll
    for (int r = 0; r < 4; ++r) {
        m_i[r] = -1e30f; l_i[r] = 0.f;
        oacc[r] = (f32x4){0.f, 0.f, 0.f, 0.f};
    }

    for (int s0 = 0; s0 < SEQ_L; s0 += 64) {
        __syncthreads();
        // K tile: linear LDS dest, src-swizzled
#pragma unroll
        for (int i = 0; i < 2; ++i) {
            const int rb = wid * 16 + i * 8;
            const int r  = rb + (lane >> 3);
            const int gc = (lane & 7) ^ (r & 7);
            __builtin_amdgcn_global_load_lds(AS1C(kg + (size_t)(s0 + r) * 3072 + gc * 8),
                                             AS3(&Kl[rb * 64]), 16, 0, 0);
        }
        // V tile transposed via registers
        {
            const int s = tid >> 2, d0 = (tid & 3) * 16;
            const u16* src = vg + (size_t)(s0 + s) * 3072 + d0;
            union { bf16x8 v; u16 u[8]; } a0, a1;
            a0.v = *(const bf16x8*)(src);
            a1.v = *(const bf16x8*)(src + 8);
#pragma unroll
            for (int uu = 0; uu < 8; ++uu) {
                const int d1 = d0 + uu, d2 = d0 + 8 + uu;
                Vt[d1 * 64 + (((s >> 3) ^ (d1 & 7)) << 3) + (s & 7)] = a0.u[uu];
                Vt[d2 * 64 + (((s >> 3) ^ (d2 & 7)) << 3) + (s & 7)] = a1.u[uu];
            }
        }
        __syncthreads();

        // S = Q K^T (wave's 16 q-rows x 64 s-cols)
        f32x4 sacc[4];
#pragma unroll
        for (int f = 0; f < 4; ++f) sacc[f] = (f32x4){0.f, 0.f, 0.f, 0.f};
#pragma unroll
        for (int ks = 0; ks < 2; ++ks)
#pragma unroll
            for (int f = 0; f < 4; ++f) {
                const int row = f * 16 + l15;
                const int ch  = (ks * 4 + l16) ^ (row & 7);
                bf16x8 kb = *(const bf16x8*)&Kl[row * 64 + ch * 8];
                sacc[f] = __builtin_amdgcn_mfma_f32_16x16x32_bf16(qa[ks], kb, sacc[f], 0, 0, 0);
            }
#pragma unroll
        for (int f = 0; f < 4; ++f) sacc[f] *= 0.125f;

        // online softmax: rows = l16*4+r, 16 lanes (l15) hold the 64 s-cols
#pragma unroll
        for (int r = 0; r < 4; ++r) {
            float mx = fmaxf(fmaxf(sacc[0][r], sacc[1][r]), fmaxf(sacc[2][r], sacc[3][r]));
            mx = fmaxf(mx, __shfl_xor(mx, 1));
            mx = fmaxf(mx, __shfl_xor(mx, 2));
            mx = fmaxf(mx, __shfl_xor(mx, 4));
            mx = fmaxf(mx, __shfl_xor(mx, 8));
            const float mnew = fmaxf(m_i[r], mx);
            const float corr = __expf(m_i[r] - mnew);
            float rs = 0.f;
#pragma unroll
            for (int f = 0; f < 4; ++f) {
                const float p = __expf(sacc[f][r] - mnew);
                sacc[f][r] = p; rs += p;
            }
            rs += __shfl_xor(rs, 1);
            rs += __shfl_xor(rs, 2);
            rs += __shfl_xor(rs, 4);
            rs += __shfl_xor(rs, 8);
            l_i[r] = l_i[r] * corr + rs;
            m_i[r] = mnew;
#pragma unroll
            for (int f2 = 0; f2 < 4; ++f2) oacc[f2][r] *= corr;
        }

        // P -> bf16 -> per-wave LDS tile [q16][s64]
#pragma unroll
        for (int f = 0; f < 4; ++f)
#pragma unroll
            for (int r = 0; r < 4; ++r) {
                const int row = l16 * 4 + r;
                const int col = f * 16 + l15;
                const int ch  = (col >> 3) ^ (row & 7);
                Pl[wid][row * 64 + ch * 8 + (col & 7)] = f2bf(sacc[f][r]);
            }
        __syncthreads();

        // O += P V
#pragma unroll
        for (int ks = 0; ks < 2; ++ks) {
            const int pch = (ks * 4 + l16) ^ (l15 & 7);
            bf16x8 pa = *(const bf16x8*)&Pl[wid][l15 * 64 + pch * 8];
#pragma unroll
            for (int f2 = 0; f2 < 4; ++f2) {
                const int d  = f2 * 16 + l15;
                const int ch = (ks * 4 + l16) ^ (d & 7);
                bf16x8 vb = *(const bf16x8*)&Vt[d * 64 + ch * 8];
                oacc[f2] = __builtin_amdgcn_mfma_f32_16x16x32_bf16(pa, vb, oacc[f2], 0, 0, 0);
            }
        }
    }

#pragma unroll
    for (int r = 0; r < 4; ++r) {
        const float inv = 1.f / l_i[r];
        const size_t row = tb + q0 + wid * 16 + l16 * 4 + r;
#pragma unroll
        for (int f2 = 0; f2 < 4; ++f2)
            ao[row * 1024 + ho + f2 * 16 + l15] = f2bf(oacc[f2][r] * inv);
    }
}

// ---------------------------------------------------------------------------
// out_f32 = LN(x_f32 + y_bf16); optionally also bf16 copy. Block per token.
// ---------------------------------------------------------------------------
template<int WB>
__global__ __launch_bounds__(256)
void add_ln(const float* __restrict__ x, const u16* __restrict__ y,
            const float* __restrict__ g, const float* __restrict__ be,
            float* __restrict__ outf, u16* __restrict__ outb)
{
    __shared__ float red[4];
    const int t = blockIdx.x, tid = threadIdx.x;
    const int c = tid * 4, lane = tid & 63, wv = tid >> 6;

    float4 a = *(const float4*)(x + (size_t)t * D_MODEL + c);
    ushort4 yb = *(const ushort4*)(y + (size_t)t * D_MODEL + c);
    float s[4] = {a.x + bf2f(yb.x), a.y + bf2f(yb.y), a.z + bf2f(yb.z), a.w + bf2f(yb.w)};

    float ps = s[0] + s[1] + s[2] + s[3];
#pragma unroll
    for (int off = 32; off > 0; off >>= 1) ps += __shfl_down(ps, off);
    if (lane == 0) red[wv] = ps;
    __syncthreads();
    const float mean = (red[0] + red[1] + red[2] + red[3]) * (1.f / D_MODEL);
    __syncthreads();

    float pv = 0.f;
#pragma unroll
    for (int u = 0; u < 4; ++u) { float d = s[u] - mean; pv += d * d; }
#pragma unroll
    for (int off = 32; off > 0; off >>= 1) pv += __shfl_down(pv, off);
    if (lane == 0) red[wv] = pv;
    __syncthreads();
    const float var = (red[0] + red[1] + red[2] + red[3]) * (1.f / D_MODEL);
    const float inv = rsqrtf(var + 1e-5f);

    float4 g4 = *(const float4*)(g + c);
    float4 b4 = *(const float4*)(be + c);
    float o[4];
#pragma unroll
    for (int u = 0; u < 4; ++u) o[u] = (s[u] - mean) * inv;
    float4 of = {o[0] * g4.x + b4.x, o[1] * g4.y + b4.y, o[2] * g4.z + b4.z, o[3] * g4.w + b4.w};
    *(float4*)(outf + (size_t)t * D_MODEL + c) = of;
    if (WB) {
        ushort4 ob = {f2bf(of.x), f2bf(of.y), f2bf(of.z), f2bf(of.w)};
        *(ushort4*)(outb + (size_t)t * D_MODEL + c) = ob;
    }
}

// ---------------------------------------------------------------------------
// fp32 [K][N] -> bf16 [N][K] transpose (64x64 tiles).
// ---------------------------------------------------------------------------
__global__ __launch_bounds__(256)
void transpose_cvt(const float* __restrict__ src, u16* __restrict__ dst, int K, int N)
{
    __shared__ float T[64][65];
    const int tid = threadIdx.x;
    const int k0 = blockIdx.y * 64, n0 = blockIdx.x * 64;
    const int rr = tid >> 4, cc = (tid & 15) * 4;
#pragma unroll
    for (int u = 0; u < 4; ++u) {
        const float4 v = *(const float4*)(src + (size_t)(k0 + rr + u * 16) * N + n0 + cc);
        T[rr + u * 16][cc + 0] = v.x; T[rr + u * 16][cc + 1] = v.y;
        T[rr + u * 16][cc + 2] = v.z; T[rr + u * 16][cc + 3] = v.w;
    }
    __syncthreads();
#pragma unroll
    for (int u = 0; u < 4; ++u) {
        const int n = rr + u * 16;
        ushort4 o;
        o.x = f2bf(T[cc + 0][n]); o.y = f2bf(T[cc + 1][n]);
        o.z = f2bf(T[cc + 2][n]); o.w = f2bf(T[cc + 3][n]);
        *(ushort4*)(dst + (size_t)(n0 + n) * K + k0 + cc) = o;
    }
}

__global__ __launch_bounds__(256)
void cvt_bf16(const float* __restrict__ src, u16* __restrict__ dst, int n)
{
    const int i = (blockIdx.x * 256 + threadIdx.x) * 4;
    if (i < n) {
        float4 v = *(const float4*)(src + i);
        ushort4 o = {f2bf(v.x), f2bf(v.y), f2bf(v.z), f2bf(v.w)};
        *(ushort4*)(dst + i) = o;
    }
}

__global__ __launch_bounds__(256)
void concat3(const float* __restrict__ a, const float* __restrict__ b,
             const float* __restrict__ c, float* __restrict__ dst)
{
    const int i = blockIdx.x * 256 + threadIdx.x;
    if (i < 3072) dst[i] = i < 1024 ? a[i] : (i < 2048 ? b[i - 1024] : c[i - 2048]);
}

// ---------------------------------------------------------------------------
extern "C" void kernel_launch(void* const* d_in, const int* in_sizes, int n_in,
                              void* d_out, int out_size, void* d_ws, size_t ws_size,
                              hipStream_t stream)
{
    (void)in_sizes; (void)n_in; (void)out_size; (void)ws_size;

    const float* x   = (const float*)d_in[0];
    const float* Wq  = (const float*)d_in[1];
    const float* bq  = (const float*)d_in[2];
    const float* Wk  = (const float*)d_in[3];
    const float* bk  = (const float*)d_in[4];
    const float* Wv  = (const float*)d_in[5];
    const float* bv  = (const float*)d_in[6];
    const float* Wm  = (const float*)d_in[7];
    const float* bm  = (const float*)d_in[8];
    const float* W1  = (const float*)d_in[9];
    const float* b1  = (const float*)d_in[10];
    const float* W2  = (const float*)d_in[11];
    const float* b2  = (const float*)d_in[12];
    const float* g1  = (const float*)d_in[13];
    const float* be1 = (const float*)d_in[14];
    const float* g2  = (const float*)d_in[15];
    const float* be2 = (const float*)d_in[16];
    float* out = (float*)d_out;

    char* base = (char*)d_ws;
    const size_t MB = 1u << 20;
    u16*   wqkv_t = (u16*)(base);              //  0..6MB : [3072][1024]
    u16*   wm_t   = (u16*)(base + 6 * MB);     //  6..8MB : [1024][1024]
    u16*   w1_t   = (u16*)(base + 8 * MB);     //  8..16MB: [4096][1024]
    u16*   w2_t   = (u16*)(base + 16 * MB);    // 16..24MB: [1024][4096]
    float* bqkv   = (float*)(base + 24 * MB);  // 12KB
    u16*   xb     = (u16*)(base + 25 * MB);    // 25..33MB (dead after QKV)
    u16*   qkv    = (u16*)(base + 33 * MB);    // 33..57MB [4096][3072]
    u16*   ao     = (u16*)(base + 57 * MB);    // 57..65MB
    u16*   f1     = (u16*)(base + 33 * MB);    // alias qkv+ao: 33..65MB
    u16*   msg    = (u16*)(base + 25 * MB);    // alias xb (dead after LN1)
    u16*   ffn    = (u16*)(base + 25 * MB);    // alias msg (dead after LN1)
    float* hf     = (float*)(base + 65 * MB);  // 65..81MB
    u16*   hb     = (u16*)(base + 81 * MB);    // 81..89MB

    dim3 blk(256);
    transpose_cvt<<<dim3(16, 16), blk, 0, stream>>>(Wq, wqkv_t,                 1024, 1024);
    transpose_cvt<<<dim3(16, 16), blk, 0, stream>>>(Wk, wqkv_t + 1024 * 1024,   1024, 1024);
    transpose_cvt<<<dim3(16, 16), blk, 0, stream>>>(Wv, wqkv_t + 2 * 1024 * 1024, 1024, 1024);
    transpose_cvt<<<dim3(16, 16), blk, 0, stream>>>(Wm, wm_t, 1024, 1024);
    transpose_cvt<<<dim3(64, 16), blk, 0, stream>>>(W1, w1_t, 1024, 4096);
    transpose_cvt<<<dim3(16, 64), blk, 0, stream>>>(W2, w2_t, 4096, 1024);
    concat3<<<dim3(12), blk, 0, stream>>>(bq, bk, bv, bqkv);
    cvt_bf16<<<dim3(4096), blk, 0, stream>>>(x, xb, N_TOK * D_MODEL);

    gemm_bt<4, 0, 1><<<dim3(24, 32), blk, 0, stream>>>(xb, wqkv_t, bqkv, qkv, N_TOK, 3072, 1024);
    attn_mfma<<<dim3(SEQ_L / 64, 32), blk, 0, stream>>>(qkv, ao);
    gemm_bt<2, 0, 1><<<dim3(8, 64), blk, 0, stream>>>(ao, wm_t, bm, msg, N_TOK, 1024, 1024);
    add_ln<1><<<dim3(N_TOK), blk, 0, stream>>>(x, msg, g1, be1, hf, hb);
    gemm_bt<4, 1, 1><<<dim3(32, 32), blk, 0, stream>>>(hb, w1_t, b1, f1, N_TOK, FF_DIM, 1024);
    gemm_bt<2, 0, 1><<<dim3(8, 64), blk, 0, stream>>>(f1, w2_t, b2, ffn, N_TOK, 1024, FF_DIM);
    add_ln<0><<<dim3(N_TOK), blk, 0, stream>>>(hf, ffn, g2, be2, out, nullptr);
}

// Round 3
// 283.041 us; speedup vs baseline: 7.0711x; 1.2160x over previous
//
#include <hip/hip_runtime.h>

#define D_MODEL 1024
#define N_TOK   4096
#define HEADS   16
#define FF_DIM  4096
#define SEQ_L   2048

typedef unsigned short u16;
typedef unsigned int   u32;
typedef __bf16 bf16x8 __attribute__((ext_vector_type(8)));
typedef float  f32x4  __attribute__((ext_vector_type(4)));

#define AS1C(p) ((const __attribute__((address_space(1))) void*)(p))
#define AS3(p)  ((__attribute__((address_space(3))) void*)(p))

__device__ __forceinline__ u16 f2bf(float f) {
    union { float f; unsigned u; } c; c.f = f;
    return (u16)((c.u + 0x7fffu + ((c.u >> 16) & 1u)) >> 16);   // RNE
}
__device__ __forceinline__ float bf2f(u16 b) {
    union { unsigned u; float f; } c; c.u = ((unsigned)b) << 16;
    return c.f;
}
__device__ __forceinline__ u32 cvt_pk_bf16(float lo, float hi) {
    u32 r;
    asm("v_cvt_pk_bf16_f32 %0, %1, %2" : "=v"(r) : "v"(lo), "v"(hi));
    return r;
}

// ---------------------------------------------------------------------------
// bf16 GEMM, C[M,N] = A[M,K] @ Bt[N,K]^T + bias, optional ReLU. (unchanged)
// ---------------------------------------------------------------------------
template<int MFR, int RELU, int OUT_BF16>
__global__ __launch_bounds__(256)
void gemm_bt(const u16* __restrict__ A, const u16* __restrict__ Bt,
             const float* __restrict__ bias, void* __restrict__ Cv,
             int M, int N, int K)
{
    constexpr int BM = MFR * 32;
    __shared__ u16 As[BM * 64];
    __shared__ u16 Bs[128 * 64];

    const int tid  = threadIdx.x;
    const int wid  = tid >> 6, lane = tid & 63;
    const int wr   = wid >> 1, wc = wid & 1;
    const int l15  = lane & 15, l16 = lane >> 4;
    const int r0   = blockIdx.y * BM, c0 = blockIdx.x * 128;

    f32x4 acc[MFR][4];
#pragma unroll
    for (int m = 0; m < MFR; ++m)
#pragma unroll
        for (int n = 0; n < 4; ++n) acc[m][n] = (f32x4){0.f, 0.f, 0.f, 0.f};

    for (int k0 = 0; k0 < K; k0 += 64) {
        __syncthreads();
#pragma unroll
        for (int i = 0; i < BM / 32; ++i) {
            const int rb = wid * (BM / 4) + i * 8;
            const int r  = rb + (lane >> 3);
            const int gc = (lane & 7) ^ (r & 7);
            __builtin_amdgcn_global_load_lds(AS1C(A + (size_t)(r0 + r) * K + k0 + gc * 8),
                                             AS3(&As[rb * 64]), 16, 0, 0);
        }
#pragma unroll
        for (int i = 0; i < 4; ++i) {
            const int rb = wid * 32 + i * 8;
            const int r  = rb + (lane >> 3);
            const int gc = (lane & 7) ^ (r & 7);
            __builtin_amdgcn_global_load_lds(AS1C(Bt + (size_t)(c0 + r) * K + k0 + gc * 8),
                                             AS3(&Bs[rb * 64]), 16, 0, 0);
        }
        __syncthreads();
#pragma unroll
        for (int ks = 0; ks < 2; ++ks) {
            bf16x8 af[MFR], bb[4];
#pragma unroll
            for (int m = 0; m < MFR; ++m) {
                const int row = wr * (MFR * 16) + m * 16 + l15;
                const int ch  = (ks * 4 + l16) ^ (row & 7);
                af[m] = *(const bf16x8*)&As[row * 64 + ch * 8];
            }
#pragma unroll
            for (int n = 0; n < 4; ++n) {
                const int row = wc * 64 + n * 16 + l15;
                const int ch  = (ks * 4 + l16) ^ (row & 7);
                bb[n] = *(const bf16x8*)&Bs[row * 64 + ch * 8];
            }
#pragma unroll
            for (int m = 0; m < MFR; ++m)
#pragma unroll
                for (int n = 0; n < 4; ++n)
                    acc[m][n] = __builtin_amdgcn_mfma_f32_16x16x32_bf16(af[m], bb[n], acc[m][n], 0, 0, 0);
        }
    }

#pragma unroll
    for (int n = 0; n < 4; ++n) {
        const int col = c0 + wc * 64 + n * 16 + l15;
        const float bv = bias[col];
#pragma unroll
        for (int m = 0; m < MFR; ++m) {
#pragma unroll
            for (int r = 0; r < 4; ++r) {
                const size_t row = (size_t)(r0 + wr * (MFR * 16) + m * 16 + l16 * 4 + r);
                float v = acc[m][n][r] + bv;
                if (RELU) v = fmaxf(v, 0.f);
                if (OUT_BF16) ((u16*)Cv)[row * N + col] = f2bf(v);
                else          ((float*)Cv)[row * N + col] = v;
            }
        }
    }
}

// ---------------------------------------------------------------------------
// MFMA flash attention v3: swapped QK^T (lane-local P rows), zero-shuffle PV
// via k-order permutation, packed-pair V in LDS, base-2 softmax + defer-max.
// ---------------------------------------------------------------------------
__global__ __launch_bounds__(256)
void attn_mfma(const u16* __restrict__ qkv, u16* __restrict__ ao)
{
    __shared__ u16 Kl[64 * 64];       // [s][d] bf16, chunk^(s&7) swizzle
    __shared__ u32 Vt[64 * 32];       // [d][s/2] packed (s even, s odd)

    const int tid = threadIdx.x;
    const int wid = tid >> 6, lane = tid & 63;
    const int l15 = lane & 15, l16 = lane >> 4;
    const int bh  = blockIdx.y, b = bh >> 4, h = bh & 15;
    const int ho  = h * 64;
    const size_t tb = (size_t)b * SEQ_L;
    const int q0  = blockIdx.x * 64;

    const u16* qg = qkv + (tb + q0) * 3072 + ho;
    const u16* kg = qkv + tb * 3072 + 1024 + ho;
    const u16* vg = qkv + tb * 3072 + 2048 + ho;

    // Q fragments (B-operand): q = wave row l15, k = d = ks*32 + l16*8..+7
    bf16x8 qa[2];
#pragma unroll
    for (int ks = 0; ks < 2; ++ks)
        qa[ks] = *(const bf16x8*)(qg + (size_t)(wid * 16 + l15) * 3072 + ks * 32 + l16 * 8);

    // V staging assignment: row-pair rp = lane&31, 16B chunk vc
    const int rp = lane & 31;
    const int vc = wid * 2 + (lane >> 5);

    f32x4 oacc[4];
#pragma unroll
    for (int f = 0; f < 4; ++f) oacc[f] = (f32x4){0.f, 0.f, 0.f, 0.f};
    float m_c = -1e30f, l_c = 0.f;

    const float SC = 0.18033688f;     // (1/8) * log2(e)

    for (int s0 = 0; s0 < SEQ_L; s0 += 64) {
        // issue V global loads early (no LDS hazard)
        union { bf16x8 v; u16 u[8]; } ua, ub;
        ua.v = *(const bf16x8*)(vg + (size_t)(s0 + 2 * rp) * 3072 + vc * 8);
        ub.v = *(const bf16x8*)(vg + (size_t)(s0 + 2 * rp + 1) * 3072 + vc * 8);

        __syncthreads();              // previous tile fully consumed
        // K tile: linear LDS dest, src chunk-swizzled
#pragma unroll
        for (int i = 0; i < 2; ++i) {
            const int rb = wid * 16 + i * 8;
            const int r  = rb + (lane >> 3);
            const int gc = (lane & 7) ^ (r & 7);
            __builtin_amdgcn_global_load_lds(AS1C(kg + (size_t)(s0 + r) * 3072 + gc * 8),
                                             AS3(&Kl[rb * 64]), 16, 0, 0);
        }
        // V: packed pairs, swizzled dword index
#pragma unroll
        for (int e = 0; e < 8; ++e) {
            const int d = vc * 8 + e;
            const int w = rp ^ (((d & 7) << 2) ^ ((d >> 3) << 1));
            Vt[d * 32 + w] = (u32)ua.u[e] | ((u32)ub.u[e] << 16);
        }
        __syncthreads();

        // S^T = K Q^T : sacc[f][r] = S[s = f*16 + l16*4 + r][q = l15]
        f32x4 sacc[4];
#pragma unroll
        for (int f = 0; f < 4; ++f) sacc[f] = (f32x4){0.f, 0.f, 0.f, 0.f};
#pragma unroll
        for (int ks = 0; ks < 2; ++ks)
#pragma unroll
            for (int f = 0; f < 4; ++f) {
                const int row = f * 16 + l15;
                const int ch  = (ks * 4 + l16) ^ (row & 7);
                bf16x8 kb = *(const bf16x8*)&Kl[row * 64 + ch * 8];
                sacc[f] = __builtin_amdgcn_mfma_f32_16x16x32_bf16(kb, qa[ks], sacc[f], 0, 0, 0);
            }
#pragma unroll
        for (int f = 0; f < 4; ++f) sacc[f] *= SC;

        // per-lane softmax over the 16 held s-values (all for q = l15)
        float mx = sacc[0][0];
#pragma unroll
        for (int f = 0; f < 4; ++f)
#pragma unroll
            for (int r = 0; r < 4; ++r) mx = fmaxf(mx, sacc[f][r]);
        mx = fmaxf(mx, __shfl_xor(mx, 16));
        mx = fmaxf(mx, __shfl_xor(mx, 32));

        if (__any(mx > m_c + 8.f)) {                 // defer-max
            const float mnew = fmaxf(m_c, mx);
            const float corr = __builtin_exp2f(m_c - mnew);
            m_c = mnew;
            l_c *= corr;
            // oacc rows are q = l16*4 + r -> fetch that q's corr
#pragma unroll
            for (int r = 0; r < 4; ++r) {
                const float cr = __shfl(corr, l16 * 4 + r);
#pragma unroll
                for (int f = 0; f < 4; ++f) oacc[f][r] *= cr;
            }
        }

        float rs = 0.f;
#pragma unroll
        for (int f = 0; f < 4; ++f)
#pragma unroll
            for (int r = 0; r < 4; ++r) {
                const float p = __builtin_exp2f(sacc[f][r] - m_c);
                sacc[f][r] = p; rs += p;
            }
        rs += __shfl_xor(rs, 16);
        rs += __shfl_xor(rs, 32);
        l_c += rs;

        // pack P to bf16 pairs: pk[f][e] = (p[f][2e], p[f][2e+1])
        u32 pk[4][2];
#pragma unroll
        for (int f = 0; f < 4; ++f) {
            pk[f][0] = cvt_pk_bf16(sacc[f][0], sacc[f][1]);
            pk[f][1] = cvt_pk_bf16(sacc[f][2], sacc[f][3]);
        }

        // O += P V with k-order sigma(l16,j) = 32S + (j>>2)*16 + l16*4 + (j&3)
#pragma unroll
        for (int S = 0; S < 2; ++S) {
            union { bf16x8 v; u32 u[4]; } af;
            af.u[0] = pk[2 * S][0];     af.u[1] = pk[2 * S][1];
            af.u[2] = pk[2 * S + 1][0]; af.u[3] = pk[2 * S + 1][1];
#pragma unroll
            for (int f2 = 0; f2 < 4; ++f2) {
                const int d = f2 * 16 + l15;
                const int swzd = ((d & 7) << 2) ^ ((d >> 3) << 1);
                union { bf16x8 v; uint2 u[2]; } vb;
                vb.u[0] = *(const uint2*)&Vt[d * 32 + ((16 * S + 2 * l16) ^ swzd)];
                vb.u[1] = *(const uint2*)&Vt[d * 32 + ((16 * S + 8 + 2 * l16) ^ swzd)];
                oacc[f2] = __builtin_amdgcn_mfma_f32_16x16x32_bf16(af.v, vb.v, oacc[f2], 0, 0, 0);
            }
        }
    }

    // epilogue: O rows q = l16*4 + r, cols d = f2*16 + l15
#pragma unroll
    for (int r = 0; r < 4; ++r) {
        const float ld  = __shfl(l_c, l16 * 4 + r);
        const float inv = 1.f / ld;
        const size_t row = tb + q0 + wid * 16 + l16 * 4 + r;
#pragma unroll
        for (int f2 = 0; f2 < 4; ++f2)
            ao[row * 1024 + ho + f2 * 16 + l15] = f2bf(oacc[f2][r] * inv);
    }
}

// ---------------------------------------------------------------------------
// out_f32 = LN(x_f32 + y_bf16); optionally also bf16 copy. (unchanged)
// ---------------------------------------------------------------------------
template<int WB>
__global__ __launch_bounds__(256)
void add_ln(const float* __restrict__ x, const u16* __restrict__ y,
            const float* __restrict__ g, const float* __restrict__ be,
            float* __restrict__ outf, u16* __restrict__ outb)
{
    __shared__ float red[4];
    const int t = blockIdx.x, tid = threadIdx.x;
    const int c = tid * 4, lane = tid & 63, wv = tid >> 6;

    float4 a = *(const float4*)(x + (size_t)t * D_MODEL + c);
    ushort4 yb = *(const ushort4*)(y + (size_t)t * D_MODEL + c);
    float s[4] = {a.x + bf2f(yb.x), a.y + bf2f(yb.y), a.z + bf2f(yb.z), a.w + bf2f(yb.w)};

    float ps = s[0] + s[1] + s[2] + s[3];
#pragma unroll
    for (int off = 32; off > 0; off >>= 1) ps += __shfl_down(ps, off);
    if (lane == 0) red[wv] = ps;
    __syncthreads();
    const float mean = (red[0] + red[1] + red[2] + red[3]) * (1.f / D_MODEL);
    __syncthreads();

    float pv = 0.f;
#pragma unroll
    for (int u = 0; u < 4; ++u) { float d = s[u] - mean; pv += d * d; }
#pragma unroll
    for (int off = 32; off > 0; off >>= 1) pv += __shfl_down(pv, off);
    if (lane == 0) red[wv] = pv;
    __syncthreads();
    const float var = (red[0] + red[1] + red[2] + red[3]) * (1.f / D_MODEL);
    const float inv = rsqrtf(var + 1e-5f);

    float4 g4 = *(const float4*)(g + c);
    float4 b4 = *(const float4*)(be + c);
    float o[4];
#pragma unroll
    for (int u = 0; u < 4; ++u) o[u] = (s[u] - mean) * inv;
    float4 of = {o[0] * g4.x + b4.x, o[1] * g4.y + b4.y, o[2] * g4.z + b4.z, o[3] * g4.w + b4.w};
    *(float4*)(outf + (size_t)t * D_MODEL + c) = of;
    if (WB) {
        ushort4 ob = {f2bf(of.x), f2bf(of.y), f2bf(of.z), f2bf(of.w)};
        *(ushort4*)(outb + (size_t)t * D_MODEL + c) = ob;
    }
}

// ---------------------------------------------------------------------------
// Merged preprocessing: 6 weight transposes + x cvt + bias concat, one launch.
// blocks 0..3071: 64x64 transpose tiles; 3072..7167: x cvt; 7168: bias concat.
// ---------------------------------------------------------------------------
__global__ __launch_bounds__(256)
void prep(const float* __restrict__ Wq, const float* __restrict__ Wk,
          const float* __restrict__ Wv, const float* __restrict__ Wm,
          const float* __restrict__ W1, const float* __restrict__ W2,
          const float* __restrict__ x,
          const float* __restrict__ bq, const float* __restrict__ bk,
          const float* __restrict__ bv,
          u16* __restrict__ wqkv_t, u16* __restrict__ wm_t,
          u16* __restrict__ w1_t, u16* __restrict__ w2_t,
          u16* __restrict__ xb, float* __restrict__ bqkv)
{
    const int blk = blockIdx.x, tid = threadIdx.x;
    if (blk < 3072) {
        __shared__ float T[64][65];
        const float* src; u16* dst; int K, N, tile;
        if (blk < 256)       { src = Wq; dst = wqkv_t;               K = 1024; N = 1024; tile = blk; }
        else if (blk < 512)  { src = Wk; dst = wqkv_t + 1024 * 1024; K = 1024; N = 1024; tile = blk - 256; }
        else if (blk < 768)  { src = Wv; dst = wqkv_t + 2*1024*1024; K = 1024; N = 1024; tile = blk - 512; }
        else if (blk < 1024) { src = Wm; dst = wm_t;                 K = 1024; N = 1024; tile = blk - 768; }
        else if (blk < 2048) { src = W1; dst = w1_t;                 K = 1024; N = 4096; tile = blk - 1024; }
        else                 { src = W2; dst = w2_t;                 K = 4096; N = 1024; tile = blk - 2048; }
        const int ntn = N >> 6;
        const int n0 = (tile % ntn) * 64, k0 = (tile / ntn) * 64;
        const int rr = tid >> 4, cc = (tid & 15) * 4;
#pragma unroll
        for (int u = 0; u < 4; ++u) {
            const float4 v = *(const float4*)(src + (size_t)(k0 + rr + u * 16) * N + n0 + cc);
            T[rr + u * 16][cc + 0] = v.x; T[rr + u * 16][cc + 1] = v.y;
            T[rr + u * 16][cc + 2] = v.z; T[rr + u * 16][cc + 3] = v.w;
        }
        __syncthreads();
#pragma unroll
        for (int u = 0; u < 4; ++u) {
            const int n = rr + u * 16;
            ushort4 o;
            o.x = f2bf(T[cc + 0][n]); o.y = f2bf(T[cc + 1][n]);
            o.z = f2bf(T[cc + 2][n]); o.w = f2bf(T[cc + 3][n]);
            *(ushort4*)(dst + (size_t)(n0 + n) * K + k0 + cc) = o;
        }
    } else if (blk < 3072 + 4096) {
        const int i = (blk - 3072) * 1024 + tid * 4;
        float4 v = *(const float4*)(x + i);
        ushort4 o = {f2bf(v.x), f2bf(v.y), f2bf(v.z), f2bf(v.w)};
        *(ushort4*)(xb + i) = o;
    } else {
#pragma unroll
        for (int u = 0; u < 12; ++u) {
            const int i = u * 256 + tid;
            bqkv[i] = i < 1024 ? bq[i] : (i < 2048 ? bk[i - 1024] : bv[i - 2048]);
        }
    }
}

// ---------------------------------------------------------------------------
extern "C" void kernel_launch(void* const* d_in, const int* in_sizes, int n_in,
                              void* d_out, int out_size, void* d_ws, size_t ws_size,
                              hipStream_t stream)
{
    (void)in_sizes; (void)n_in; (void)out_size; (void)ws_size;

    const float* x   = (const float*)d_in[0];
    const float* Wq  = (const float*)d_in[1];
    const float* bq  = (const float*)d_in[2];
    const float* Wk  = (const float*)d_in[3];
    const float* bk  = (const float*)d_in[4];
    const float* Wv  = (const float*)d_in[5];
    const float* bv  = (const float*)d_in[6];
    const float* Wm  = (const float*)d_in[7];
    const float* bm  = (const float*)d_in[8];
    const float* W1  = (const float*)d_in[9];
    const float* b1  = (const float*)d_in[10];
    const float* W2  = (const float*)d_in[11];
    const float* b2  = (const float*)d_in[12];
    const float* g1  = (const float*)d_in[13];
    const float* be1 = (const float*)d_in[14];
    const float* g2  = (const float*)d_in[15];
    const float* be2 = (const float*)d_in[16];
    float* out = (float*)d_out;

    char* base = (char*)d_ws;
    const size_t MB = 1u << 20;
    u16*   wqkv_t = (u16*)(base);              //  0..6MB : [3072][1024]
    u16*   wm_t   = (u16*)(base + 6 * MB);     //  6..8MB
    u16*   w1_t   = (u16*)(base + 8 * MB);     //  8..16MB: [4096][1024]
    u16*   w2_t   = (u16*)(base + 16 * MB);    // 16..24MB: [1024][4096]
    float* bqkv   = (float*)(base + 24 * MB);
    u16*   xb     = (u16*)(base + 25 * MB);    // 25..33MB (dead after QKV)
    u16*   qkv    = (u16*)(base + 33 * MB);    // 33..57MB [4096][3072]
    u16*   ao     = (u16*)(base + 57 * MB);    // 57..65MB
    u16*   f1     = (u16*)(base + 33 * MB);    // alias qkv+ao
    u16*   msg    = (u16*)(base + 25 * MB);    // alias xb
    u16*   ffn    = (u16*)(base + 25 * MB);
    float* hf     = (float*)(base + 65 * MB);
    u16*   hb     = (u16*)(base + 81 * MB);

    dim3 blk(256);
    prep<<<dim3(3072 + 4096 + 1), blk, 0, stream>>>(Wq, Wk, Wv, Wm, W1, W2, x,
                                                    bq, bk, bv,
                                                    wqkv_t, wm_t, w1_t, w2_t, xb, bqkv);

    gemm_bt<4, 0, 1><<<dim3(24, 32), blk, 0, stream>>>(xb, wqkv_t, bqkv, qkv, N_TOK, 3072, 1024);
    attn_mfma<<<dim3(SEQ_L / 64, 32), blk, 0, stream>>>(qkv, ao);
    gemm_bt<2, 0, 1><<<dim3(8, 64), blk, 0, stream>>>(ao, wm_t, bm, msg, N_TOK, 1024, 1024);
    add_ln<1><<<dim3(N_TOK), blk, 0, stream>>>(x, msg, g1, be1, hf, hb);
    gemm_bt<4, 1, 1><<<dim3(32, 32), blk, 0, stream>>>(hb, w1_t, b1, f1, N_TOK, FF_DIM, 1024);
    gemm_bt<2, 0, 1><<<dim3(8, 64), blk, 0, stream>>>(f1, w2_t, b2, ffn, N_TOK, 1024, FF_DIM);
    add_ln<0><<<dim3(N_TOK), blk, 0, stream>>>(hf, ffn, g2, be2, out, nullptr);
}

// Round 4
// 268.066 us; speedup vs baseline: 7.4661x; 1.0559x over previous
//
#include <hip/hip_runtime.h>

#define D_MODEL 1024
#define N_TOK   4096
#define HEADS   16
#define FF_DIM  4096
#define SEQ_L   2048

typedef unsigned short u16;
typedef unsigned int   u32;
typedef __bf16 bf16x8 __attribute__((ext_vector_type(8)));
typedef float  f32x4  __attribute__((ext_vector_type(4)));

#define AS1C(p) ((const __attribute__((address_space(1))) void*)(p))
#define AS3(p)  ((__attribute__((address_space(3))) void*)(p))

__device__ __forceinline__ u16 f2bf(float f) {
    union { float f; unsigned u; } c; c.f = f;
    return (u16)((c.u + 0x7fffu + ((c.u >> 16) & 1u)) >> 16);   // RNE
}
__device__ __forceinline__ float bf2f(u16 b) {
    union { unsigned u; float f; } c; c.u = ((unsigned)b) << 16;
    return c.f;
}
__device__ __forceinline__ u32 cvt_pk_bf16(float lo, float hi) {
    u32 r;
    asm("v_cvt_pk_bf16_f32 %0, %1, %2" : "=v"(r) : "v"(lo), "v"(hi));
    return r;
}

// ---------------------------------------------------------------------------
// Pipelined 256x256 GEMM (counted-vmcnt, 4 phases/K-tile, double-buffer LDS).
// 512 thr = 8 waves (2M x 4N), wave tile 128x64. C = A @ Bt^T + bias (+ReLU).
// Prefetch: B(t+1) issued at p0, A(t+2) at p3 -> vmcnt(4) at group start
// keeps A(t+1) in flight (never drains in main loop).
// ---------------------------------------------------------------------------
template<int RELU>
__global__ __launch_bounds__(512, 2)
void gemm_pipe(const u16* __restrict__ A, const u16* __restrict__ Bt,
               const float* __restrict__ bias, u16* __restrict__ C,
               int M, int N, int K)
{
    __shared__ u16 As[2][256 * 64];
    __shared__ u16 Bs[2][256 * 64];

    const int tid = threadIdx.x;
    const int wid = tid >> 6, lane = tid & 63;
    const int wr  = wid >> 2, wc = wid & 3;
    const int l15 = lane & 15, l16 = lane >> 4;
    const int r0  = blockIdx.y * 256, c0 = blockIdx.x * 256;

    const u16* Ab = A  + (size_t)r0 * K;
    const u16* Bb = Bt + (size_t)c0 * K;

    f32x4 acc[8][4];
#pragma unroll
    for (int m = 0; m < 8; ++m)
#pragma unroll
        for (int n = 0; n < 4; ++n) acc[m][n] = (f32x4){0.f, 0.f, 0.f, 0.f};

    auto stage = [&](u16* dst, const u16* src, int kbase) {
#pragma unroll
        for (int i = 0; i < 4; ++i) {
            const int r  = i * 64 + (tid >> 3);
            const int gc = (tid & 7) ^ (r & 7);
            __builtin_amdgcn_global_load_lds(AS1C(src + (size_t)r * K + kbase + gc * 8),
                                             AS3(dst + (i * 64 + (wid << 3)) * 64), 16, 0, 0);
        }
    };

    bf16x8 af[4][2], bbA[2][2], bbB[2][2];

    auto ldAf = [&](const u16* sl, int mh) {
#pragma unroll
        for (int m = 0; m < 4; ++m) {
            const int row = wr * 128 + (mh * 4 + m) * 16 + l15;
#pragma unroll
            for (int ks = 0; ks < 2; ++ks) {
                const int ch = (ks * 4 + l16) ^ (row & 7);
                af[m][ks] = *(const bf16x8*)&sl[row * 64 + ch * 8];
            }
        }
    };
    auto ldBf = [&](const u16* sl, int pair, bf16x8 (&bb)[2][2]) {
#pragma unroll
        for (int n = 0; n < 2; ++n) {
            const int row = wc * 64 + (pair * 2 + n) * 16 + l15;
#pragma unroll
            for (int ks = 0; ks < 2; ++ks) {
                const int ch = (ks * 4 + l16) ^ (row & 7);
                bb[n][ks] = *(const bf16x8*)&sl[row * 64 + ch * 8];
            }
        }
    };
    auto mm16 = [&](int mh, int pair, bf16x8 (&bb)[2][2]) {
        __builtin_amdgcn_s_setprio(1);
#pragma unroll
        for (int ks = 0; ks < 2; ++ks)
#pragma unroll
            for (int m = 0; m < 4; ++m)
#pragma unroll
                for (int n = 0; n < 2; ++n)
                    acc[mh * 4 + m][pair * 2 + n] =
                        __builtin_amdgcn_mfma_f32_16x16x32_bf16(af[m][ks], bb[n][ks],
                                                                acc[mh * 4 + m][pair * 2 + n], 0, 0, 0);
        __builtin_amdgcn_s_setprio(0);
    };

    const int nt = K >> 6;
    // prologue: A(0), B(0), A(1)
    stage(&As[0][0], Ab, 0);
    stage(&Bs[0][0], Bb, 0);
    stage(&As[1][0], Ab, 64);

    for (int t = 0; t < nt; ++t) {
        u16* Asl = &As[t & 1][0];
        u16* Bsl = &Bs[t & 1][0];
        u16* Aso = &As[t & 1][0];          // A(t+2) goes into same slot
        u16* Bso = &Bs[(t + 1) & 1][0];

        // ---- p0 ----
        if (t + 1 < nt) { asm volatile("s_waitcnt vmcnt(4)" ::: "memory"); }
        else            { asm volatile("s_waitcnt vmcnt(0)" ::: "memory"); }
        __builtin_amdgcn_s_barrier();
        ldAf(Asl, 0);
        ldBf(Bsl, 0, bbA);
        if (t + 1 < nt) stage(Bso, Bb, (t + 1) * 64);
        __builtin_amdgcn_s_barrier();
        mm16(0, 0, bbA);
        __builtin_amdgcn_s_barrier();
        // ---- p1 ----
        ldBf(Bsl, 1, bbB);
        mm16(0, 1, bbB);
        __builtin_amdgcn_s_barrier();
        // ---- p2 ----
        ldAf(Asl, 1);
        mm16(1, 0, bbA);
        __builtin_amdgcn_s_barrier();
        // ---- p3 ----
        if (t + 2 < nt) stage(Aso, Ab, (t + 2) * 64);
        mm16(1, 1, bbB);
        __builtin_amdgcn_s_barrier();
    }

#pragma unroll
    for (int n = 0; n < 4; ++n) {
        const int col = c0 + wc * 64 + n * 16 + l15;
        const float bv = bias[col];
#pragma unroll
        for (int m = 0; m < 8; ++m) {
#pragma unroll
            for (int r = 0; r < 4; ++r) {
                const size_t row = (size_t)(r0 + wr * 128 + m * 16 + l16 * 4 + r);
                float v = acc[m][n][r] + bv;
                if (RELU) v = fmaxf(v, 0.f);
                C[row * N + col] = f2bf(v);
            }
        }
    }
}

// ---------------------------------------------------------------------------
// bf16 GEMM (m97 2-barrier structure) — kept for the N=1024 GEMMs.
// ---------------------------------------------------------------------------
template<int MFR, int RELU, int OUT_BF16>
__global__ __launch_bounds__(256)
void gemm_bt(const u16* __restrict__ A, const u16* __restrict__ Bt,
             const float* __restrict__ bias, void* __restrict__ Cv,
             int M, int N, int K)
{
    constexpr int BM = MFR * 32;
    __shared__ u16 As[BM * 64];
    __shared__ u16 Bs[128 * 64];

    const int tid  = threadIdx.x;
    const int wid  = tid >> 6, lane = tid & 63;
    const int wr   = wid >> 1, wc = wid & 1;
    const int l15  = lane & 15, l16 = lane >> 4;
    const int r0   = blockIdx.y * BM, c0 = blockIdx.x * 128;

    f32x4 acc[MFR][4];
#pragma unroll
    for (int m = 0; m < MFR; ++m)
#pragma unroll
        for (int n = 0; n < 4; ++n) acc[m][n] = (f32x4){0.f, 0.f, 0.f, 0.f};

    for (int k0 = 0; k0 < K; k0 += 64) {
        __syncthreads();
#pragma unroll
        for (int i = 0; i < BM / 32; ++i) {
            const int rb = wid * (BM / 4) + i * 8;
            const int r  = rb + (lane >> 3);
            const int gc = (lane & 7) ^ (r & 7);
            __builtin_amdgcn_global_load_lds(AS1C(A + (size_t)(r0 + r) * K + k0 + gc * 8),
                                             AS3(&As[rb * 64]), 16, 0, 0);
        }
#pragma unroll
        for (int i = 0; i < 4; ++i) {
            const int rb = wid * 32 + i * 8;
            const int r  = rb + (lane >> 3);
            const int gc = (lane & 7) ^ (r & 7);
            __builtin_amdgcn_global_load_lds(AS1C(Bt + (size_t)(c0 + r) * K + k0 + gc * 8),
                                             AS3(&Bs[rb * 64]), 16, 0, 0);
        }
        __syncthreads();
#pragma unroll
        for (int ks = 0; ks < 2; ++ks) {
            bf16x8 af[MFR], bb[4];
#pragma unroll
            for (int m = 0; m < MFR; ++m) {
                const int row = wr * (MFR * 16) + m * 16 + l15;
                const int ch  = (ks * 4 + l16) ^ (row & 7);
                af[m] = *(const bf16x8*)&As[row * 64 + ch * 8];
            }
#pragma unroll
            for (int n = 0; n < 4; ++n) {
                const int row = wc * 64 + n * 16 + l15;
                const int ch  = (ks * 4 + l16) ^ (row & 7);
                bb[n] = *(const bf16x8*)&Bs[row * 64 + ch * 8];
            }
#pragma unroll
            for (int m = 0; m < MFR; ++m)
#pragma unroll
                for (int n = 0; n < 4; ++n)
                    acc[m][n] = __builtin_amdgcn_mfma_f32_16x16x32_bf16(af[m], bb[n], acc[m][n], 0, 0, 0);
        }
    }

#pragma unroll
    for (int n = 0; n < 4; ++n) {
        const int col = c0 + wc * 64 + n * 16 + l15;
        const float bv = bias[col];
#pragma unroll
        for (int m = 0; m < MFR; ++m) {
#pragma unroll
            for (int r = 0; r < 4; ++r) {
                const size_t row = (size_t)(r0 + wr * (MFR * 16) + m * 16 + l16 * 4 + r);
                float v = acc[m][n][r] + bv;
                if (RELU) v = fmaxf(v, 0.f);
                if (OUT_BF16) ((u16*)Cv)[row * N + col] = f2bf(v);
                else          ((float*)Cv)[row * N + col] = v;
            }
        }
    }
}

// ---------------------------------------------------------------------------
// MFMA flash attention v4: 128 q-rows/block (32/wave, 2 sets), K-frags hoisted
// to regs shared across sets, Q pre-scaled, swapped QK^T, zero-shuffle PV.
// ---------------------------------------------------------------------------
__global__ __launch_bounds__(256)
void attn_mfma(const u16* __restrict__ qkv, u16* __restrict__ ao)
{
    __shared__ u16 Kl[64 * 64];       // [s][d] bf16, chunk^(s&7) swizzle
    __shared__ u32 Vt[64 * 32];       // [d][s/2] packed (s even, s odd)

    const int tid = threadIdx.x;
    const int wid = tid >> 6, lane = tid & 63;
    const int l15 = lane & 15, l16 = lane >> 4;
    const int bh  = blockIdx.y, b = bh >> 4, h = bh & 15;
    const int ho  = h * 64;
    const size_t tb = (size_t)b * SEQ_L;
    const int q0  = blockIdx.x * 128;

    const u16* qg = qkv + (tb + q0) * 3072 + ho;
    const u16* kg = qkv + tb * 3072 + 1024 + ho;
    const u16* vg = qkv + tb * 3072 + 2048 + ho;

    const float SC = 0.18033688f;     // (1/8) * log2(e)

    // Q fragments, pre-scaled by SC: q-row = wid*32 + set*16 + l15
    bf16x8 qa[2][2];
#pragma unroll
    for (int set = 0; set < 2; ++set)
#pragma unroll
        for (int ks = 0; ks < 2; ++ks) {
            union { bf16x8 v; u16 u[8]; u32 w[4]; } a, r;
            a.v = *(const bf16x8*)(qg + (size_t)(wid * 32 + set * 16 + l15) * 3072 + ks * 32 + l16 * 8);
#pragma unroll
            for (int e = 0; e < 4; ++e)
                r.w[e] = cvt_pk_bf16(bf2f(a.u[2 * e]) * SC, bf2f(a.u[2 * e + 1]) * SC);
            qa[set][ks] = r.v;
        }

    const int rp = lane & 31;
    const int vc = wid * 2 + (lane >> 5);

    f32x4 oacc[2][4];
#pragma unroll
    for (int set = 0; set < 2; ++set)
#pragma unroll
        for (int f = 0; f < 4; ++f) oacc[set][f] = (f32x4){0.f, 0.f, 0.f, 0.f};
    float m_c[2] = {-1e30f, -1e30f}, l_c[2] = {0.f, 0.f};

    for (int s0 = 0; s0 < SEQ_L; s0 += 64) {
        union { bf16x8 v; u16 u[8]; } ua, ub;
        ua.v = *(const bf16x8*)(vg + (size_t)(s0 + 2 * rp) * 3072 + vc * 8);
        ub.v = *(const bf16x8*)(vg + (size_t)(s0 + 2 * rp + 1) * 3072 + vc * 8);

        __syncthreads();
#pragma unroll
        for (int i = 0; i < 2; ++i) {
            const int rb = wid * 16 + i * 8;
            const int r  = rb + (lane >> 3);
            const int gc = (lane & 7) ^ (r & 7);
            __builtin_amdgcn_global_load_lds(AS1C(kg + (size_t)(s0 + r) * 3072 + gc * 8),
                                             AS3(&Kl[rb * 64]), 16, 0, 0);
        }
#pragma unroll
        for (int e = 0; e < 8; ++e) {
            const int d = vc * 8 + e;
            const int w = rp ^ (((d & 7) << 2) ^ ((d >> 3) << 1));
            Vt[d * 32 + w] = (u32)ua.u[e] | ((u32)ub.u[e] << 16);
        }
        __syncthreads();

        // K fragments once, shared by both q-sets
        bf16x8 kb[4][2];
#pragma unroll
        for (int f = 0; f < 4; ++f)
#pragma unroll
            for (int ks = 0; ks < 2; ++ks) {
                const int row = f * 16 + l15;
                const int ch  = (ks * 4 + l16) ^ (row & 7);
                kb[f][ks] = *(const bf16x8*)&Kl[row * 64 + ch * 8];
            }

#pragma unroll
        for (int set = 0; set < 2; ++set) {
            f32x4 sacc[4];
#pragma unroll
            for (int f = 0; f < 4; ++f) sacc[f] = (f32x4){0.f, 0.f, 0.f, 0.f};
#pragma unroll
            for (int ks = 0; ks < 2; ++ks)
#pragma unroll
                for (int f = 0; f < 4; ++f)
                    sacc[f] = __builtin_amdgcn_mfma_f32_16x16x32_bf16(kb[f][ks], qa[set][ks], sacc[f], 0, 0, 0);

            float mx = sacc[0][0];
#pragma unroll
            for (int f = 0; f < 4; ++f)
#pragma unroll
                for (int r = 0; r < 4; ++r) mx = fmaxf(mx, sacc[f][r]);
            mx = fmaxf(mx, __shfl_xor(mx, 16));
            mx = fmaxf(mx, __shfl_xor(mx, 32));

            if (__any(mx > m_c[set] + 8.f)) {
                const float mnew = fmaxf(m_c[set], mx);
                const float corr = __builtin_exp2f(m_c[set] - mnew);
                m_c[set] = mnew;
                l_c[set] *= corr;
#pragma unroll
                for (int r = 0; r < 4; ++r) {
                    const float cr = __shfl(corr, l16 * 4 + r);
#pragma unroll
                    for (int f = 0; f < 4; ++f) oacc[set][f][r] *= cr;
                }
            }

            float rs = 0.f;
#pragma unroll
            for (int f = 0; f < 4; ++f)
#pragma unroll
                for (int r = 0; r < 4; ++r) {
                    const float p = __builtin_exp2f(sacc[f][r] - m_c[set]);
                    sacc[f][r] = p; rs += p;
                }
            rs += __shfl_xor(rs, 16);
            rs += __shfl_xor(rs, 32);
            l_c[set] += rs;

            u32 pk[4][2];
#pragma unroll
            for (int f = 0; f < 4; ++f) {
                pk[f][0] = cvt_pk_bf16(sacc[f][0], sacc[f][1]);
                pk[f][1] = cvt_pk_bf16(sacc[f][2], sacc[f][3]);
            }

#pragma unroll
            for (int S = 0; S < 2; ++S) {
                union { bf16x8 v; u32 u[4]; } af;
                af.u[0] = pk[2 * S][0];     af.u[1] = pk[2 * S][1];
                af.u[2] = pk[2 * S + 1][0]; af.u[3] = pk[2 * S + 1][1];
#pragma unroll
                for (int f2 = 0; f2 < 4; ++f2) {
                    const int d = f2 * 16 + l15;
                    const int swzd = ((d & 7) << 2) ^ ((d >> 3) << 1);
                    union { bf16x8 v; uint2 u[2]; } vb;
                    vb.u[0] = *(const uint2*)&Vt[d * 32 + ((16 * S + 2 * l16) ^ swzd)];
                    vb.u[1] = *(const uint2*)&Vt[d * 32 + ((16 * S + 8 + 2 * l16) ^ swzd)];
                    oacc[set][f2] = __builtin_amdgcn_mfma_f32_16x16x32_bf16(af.v, vb.v, oacc[set][f2], 0, 0, 0);
                }
            }
        }
    }

#pragma unroll
    for (int set = 0; set < 2; ++set)
#pragma unroll
        for (int r = 0; r < 4; ++r) {
            const float ld  = __shfl(l_c[set], l16 * 4 + r);
            const float inv = 1.f / ld;
            const size_t row = tb + q0 + wid * 32 + set * 16 + l16 * 4 + r;
#pragma unroll
            for (int f2 = 0; f2 < 4; ++f2)
                ao[row * 1024 + ho + f2 * 16 + l15] = f2bf(oacc[set][f2][r] * inv);
        }
}

// ---------------------------------------------------------------------------
// out_f32 = LN(x_f32 + y_bf16); optionally also bf16 copy. (unchanged)
// ---------------------------------------------------------------------------
template<int WB>
__global__ __launch_bounds__(256)
void add_ln(const float* __restrict__ x, const u16* __restrict__ y,
            const float* __restrict__ g, const float* __restrict__ be,
            float* __restrict__ outf, u16* __restrict__ outb)
{
    __shared__ float red[4];
    const int t = blockIdx.x, tid = threadIdx.x;
    const int c = tid * 4, lane = tid & 63, wv = tid >> 6;

    float4 a = *(const float4*)(x + (size_t)t * D_MODEL + c);
    ushort4 yb = *(const ushort4*)(y + (size_t)t * D_MODEL + c);
    float s[4] = {a.x + bf2f(yb.x), a.y + bf2f(yb.y), a.z + bf2f(yb.z), a.w + bf2f(yb.w)};

    float ps = s[0] + s[1] + s[2] + s[3];
#pragma unroll
    for (int off = 32; off > 0; off >>= 1) ps += __shfl_down(ps, off);
    if (lane == 0) red[wv] = ps;
    __syncthreads();
    const float mean = (red[0] + red[1] + red[2] + red[3]) * (1.f / D_MODEL);
    __syncthreads();

    float pv = 0.f;
#pragma unroll
    for (int u = 0; u < 4; ++u) { float d = s[u] - mean; pv += d * d; }
#pragma unroll
    for (int off = 32; off > 0; off >>= 1) pv += __shfl_down(pv, off);
    if (lane == 0) red[wv] = pv;
    __syncthreads();
    const float var = (red[0] + red[1] + red[2] + red[3]) * (1.f / D_MODEL);
    const float inv = rsqrtf(var + 1e-5f);

    float4 g4 = *(const float4*)(g + c);
    float4 b4 = *(const float4*)(be + c);
    float o[4];
#pragma unroll
    for (int u = 0; u < 4; ++u) o[u] = (s[u] - mean) * inv;
    float4 of = {o[0] * g4.x + b4.x, o[1] * g4.y + b4.y, o[2] * g4.z + b4.z, o[3] * g4.w + b4.w};
    *(float4*)(outf + (size_t)t * D_MODEL + c) = of;
    if (WB) {
        ushort4 ob = {f2bf(of.x), f2bf(of.y), f2bf(of.z), f2bf(of.w)};
        *(ushort4*)(outb + (size_t)t * D_MODEL + c) = ob;
    }
}

// ---------------------------------------------------------------------------
// Merged preprocessing (unchanged).
// ---------------------------------------------------------------------------
__global__ __launch_bounds__(256)
void prep(const float* __restrict__ Wq, const float* __restrict__ Wk,
          const float* __restrict__ Wv, const float* __restrict__ Wm,
          const float* __restrict__ W1, const float* __restrict__ W2,
          const float* __restrict__ x,
          const float* __restrict__ bq, const float* __restrict__ bk,
          const float* __restrict__ bv,
          u16* __restrict__ wqkv_t, u16* __restrict__ wm_t,
          u16* __restrict__ w1_t, u16* __restrict__ w2_t,
          u16* __restrict__ xb, float* __restrict__ bqkv)
{
    const int blk = blockIdx.x, tid = threadIdx.x;
    if (blk < 3072) {
        __shared__ float T[64][65];
        const float* src; u16* dst; int K, N, tile;
        if (blk < 256)       { src = Wq; dst = wqkv_t;               K = 1024; N = 1024; tile = blk; }
        else if (blk < 512)  { src = Wk; dst = wqkv_t + 1024 * 1024; K = 1024; N = 1024; tile = blk - 256; }
        else if (blk < 768)  { src = Wv; dst = wqkv_t + 2*1024*1024; K = 1024; N = 1024; tile = blk - 512; }
        else if (blk < 1024) { src = Wm; dst = wm_t;                 K = 1024; N = 1024; tile = blk - 768; }
        else if (blk < 2048) { src = W1; dst = w1_t;                 K = 1024; N = 4096; tile = blk - 1024; }
        else                 { src = W2; dst = w2_t;                 K = 4096; N = 1024; tile = blk - 2048; }
        const int ntn = N >> 6;
        const int n0 = (tile % ntn) * 64, k0 = (tile / ntn) * 64;
        const int rr = tid >> 4, cc = (tid & 15) * 4;
#pragma unroll
        for (int u = 0; u < 4; ++u) {
            const float4 v = *(const float4*)(src + (size_t)(k0 + rr + u * 16) * N + n0 + cc);
            T[rr + u * 16][cc + 0] = v.x; T[rr + u * 16][cc + 1] = v.y;
            T[rr + u * 16][cc + 2] = v.z; T[rr + u * 16][cc + 3] = v.w;
        }
        __syncthreads();
#pragma unroll
        for (int u = 0; u < 4; ++u) {
            const int n = rr + u * 16;
            ushort4 o;
            o.x = f2bf(T[cc + 0][n]); o.y = f2bf(T[cc + 1][n]);
            o.z = f2bf(T[cc + 2][n]); o.w = f2bf(T[cc + 3][n]);
            *(ushort4*)(dst + (size_t)(n0 + n) * K + k0 + cc) = o;
        }
    } else if (blk < 3072 + 4096) {
        const int i = (blk - 3072) * 1024 + tid * 4;
        float4 v = *(const float4*)(x + i);
        ushort4 o = {f2bf(v.x), f2bf(v.y), f2bf(v.z), f2bf(v.w)};
        *(ushort4*)(xb + i) = o;
    } else {
#pragma unroll
        for (int u = 0; u < 12; ++u) {
            const int i = u * 256 + tid;
            bqkv[i] = i < 1024 ? bq[i] : (i < 2048 ? bk[i - 1024] : bv[i - 2048]);
        }
    }
}

// ---------------------------------------------------------------------------
extern "C" void kernel_launch(void* const* d_in, const int* in_sizes, int n_in,
                              void* d_out, int out_size, void* d_ws, size_t ws_size,
                              hipStream_t stream)
{
    (void)in_sizes; (void)n_in; (void)out_size; (void)ws_size;

    const float* x   = (const float*)d_in[0];
    const float* Wq  = (const float*)d_in[1];
    const float* bq  = (const float*)d_in[2];
    const float* Wk  = (const float*)d_in[3];
    const float* bk  = (const float*)d_in[4];
    const float* Wv  = (const float*)d_in[5];
    const float* bv  = (const float*)d_in[6];
    const float* Wm  = (const float*)d_in[7];
    const float* bm  = (const float*)d_in[8];
    const float* W1  = (const float*)d_in[9];
    const float* b1  = (const float*)d_in[10];
    const float* W2  = (const float*)d_in[11];
    const float* b2  = (const float*)d_in[12];
    const float* g1  = (const float*)d_in[13];
    const float* be1 = (const float*)d_in[14];
    const float* g2  = (const float*)d_in[15];
    const float* be2 = (const float*)d_in[16];
    float* out = (float*)d_out;

    char* base = (char*)d_ws;
    const size_t MB = 1u << 20;
    u16*   wqkv_t = (u16*)(base);              //  0..6MB : [3072][1024]
    u16*   wm_t   = (u16*)(base + 6 * MB);     //  6..8MB
    u16*   w1_t   = (u16*)(base + 8 * MB);     //  8..16MB: [4096][1024]
    u16*   w2_t   = (u16*)(base + 16 * MB);    // 16..24MB: [1024][4096]
    float* bqkv   = (float*)(base + 24 * MB);
    u16*   xb     = (u16*)(base + 25 * MB);    // 25..33MB (dead after QKV)
    u16*   qkv    = (u16*)(base + 33 * MB);    // 33..57MB [4096][3072]
    u16*   ao     = (u16*)(base + 57 * MB);    // 57..65MB
    u16*   f1     = (u16*)(base + 33 * MB);    // alias qkv+ao
    u16*   msg    = (u16*)(base + 25 * MB);    // alias xb
    u16*   ffn    = (u16*)(base + 25 * MB);
    float* hf     = (float*)(base + 65 * MB);
    u16*   hb     = (u16*)(base + 81 * MB);

    dim3 blk(256);
    prep<<<dim3(3072 + 4096 + 1), blk, 0, stream>>>(Wq, Wk, Wv, Wm, W1, W2, x,
                                                    bq, bk, bv,
                                                    wqkv_t, wm_t, w1_t, w2_t, xb, bqkv);

    gemm_pipe<0><<<dim3(12, 16), dim3(512), 0, stream>>>(xb, wqkv_t, bqkv, qkv, N_TOK, 3072, 1024);
    attn_mfma<<<dim3(SEQ_L / 128, 32), blk, 0, stream>>>(qkv, ao);
    gemm_bt<2, 0, 1><<<dim3(8, 64), blk, 0, stream>>>(ao, wm_t, bm, msg, N_TOK, 1024, 1024);
    add_ln<1><<<dim3(N_TOK), blk, 0, stream>>>(x, msg, g1, be1, hf, hb);
    gemm_pipe<1><<<dim3(16, 16), dim3(512), 0, stream>>>(hb, w1_t, b1, f1, N_TOK, FF_DIM, 1024);
    gemm_bt<2, 0, 1><<<dim3(8, 64), blk, 0, stream>>>(f1, w2_t, b2, ffn, N_TOK, 1024, FF_DIM);
    add_ln<0><<<dim3(N_TOK), blk, 0, stream>>>(hf, ffn, g2, be2, out, nullptr);
}

// Round 5
// 258.025 us; speedup vs baseline: 7.7567x; 1.0389x over previous
//
#include <hip/hip_runtime.h>

#define D_MODEL 1024
#define N_TOK   4096
#define HEADS   16
#define FF_DIM  4096
#define SEQ_L   2048

typedef unsigned short u16;
typedef unsigned int   u32;
typedef __bf16 bf16x8 __attribute__((ext_vector_type(8)));
typedef float  f32x4  __attribute__((ext_vector_type(4)));

#define AS1C(p) ((const __attribute__((address_space(1))) void*)(p))
#define AS3(p)  ((__attribute__((address_space(3))) void*)(p))

__device__ __forceinline__ u16 f2bf(float f) {
    union { float f; unsigned u; } c; c.f = f;
    return (u16)((c.u + 0x7fffu + ((c.u >> 16) & 1u)) >> 16);   // RNE
}
__device__ __forceinline__ float bf2f(u16 b) {
    union { unsigned u; float f; } c; c.u = ((unsigned)b) << 16;
    return c.f;
}
__device__ __forceinline__ u32 cvt_pk_bf16(float lo, float hi) {
    u32 r;
    asm("v_cvt_pk_bf16_f32 %0, %1, %2" : "=v"(r) : "v"(lo), "v"(hi));
    return r;
}
__device__ __forceinline__ float fmax3(float a, float b, float c) {
    float r;
    asm("v_max3_f32 %0, %1, %2, %3" : "=v"(r) : "v"(a), "v"(b), "v"(c));
    return r;
}

// ---------------------------------------------------------------------------
// Pipelined 256x256 GEMM (counted-vmcnt, 4 phases/K-tile, double-buffer LDS).
// 512 thr = 8 waves (2M x 4N), wave tile 128x64. XCD-swizzled grid.
// ---------------------------------------------------------------------------
template<int RELU>
__global__ __launch_bounds__(512, 2)
void gemm_pipe(const u16* __restrict__ A, const u16* __restrict__ Bt,
               const float* __restrict__ bias, u16* __restrict__ C,
               int M, int N, int K)
{
    __shared__ u16 As[2][256 * 64];
    __shared__ u16 Bs[2][256 * 64];

    const int tid = threadIdx.x;
    const int wid = tid >> 6, lane = tid & 63;
    const int wr  = wid >> 2, wc = wid & 3;
    const int l15 = lane & 15, l16 = lane >> 4;

    const int nwg = gridDim.x * gridDim.y;          // multiple of 8
    int bid = blockIdx.y * gridDim.x + blockIdx.x;
    bid = (bid & 7) * (nwg >> 3) + (bid >> 3);      // XCD-chunked, bijective
    const int r0 = (bid / gridDim.x) * 256, c0 = (bid % gridDim.x) * 256;

    const u16* Ab = A  + (size_t)r0 * K;
    const u16* Bb = Bt + (size_t)c0 * K;

    f32x4 acc[8][4];
#pragma unroll
    for (int m = 0; m < 8; ++m)
#pragma unroll
        for (int n = 0; n < 4; ++n) acc[m][n] = (f32x4){0.f, 0.f, 0.f, 0.f};

    auto stage = [&](u16* dst, const u16* src, int kbase) {
#pragma unroll
        for (int i = 0; i < 4; ++i) {
            const int r  = i * 64 + (tid >> 3);
            const int gc = (tid & 7) ^ (r & 7);
            __builtin_amdgcn_global_load_lds(AS1C(src + (size_t)r * K + kbase + gc * 8),
                                             AS3(dst + (i * 64 + (wid << 3)) * 64), 16, 0, 0);
        }
    };

    bf16x8 af[4][2], bbA[2][2], bbB[2][2];

    auto ldAf = [&](const u16* sl, int mh) {
#pragma unroll
        for (int m = 0; m < 4; ++m) {
            const int row = wr * 128 + (mh * 4 + m) * 16 + l15;
#pragma unroll
            for (int ks = 0; ks < 2; ++ks) {
                const int ch = (ks * 4 + l16) ^ (row & 7);
                af[m][ks] = *(const bf16x8*)&sl[row * 64 + ch * 8];
            }
        }
    };
    auto ldBf = [&](const u16* sl, int pair, bf16x8 (&bb)[2][2]) {
#pragma unroll
        for (int n = 0; n < 2; ++n) {
            const int row = wc * 64 + (pair * 2 + n) * 16 + l15;
#pragma unroll
            for (int ks = 0; ks < 2; ++ks) {
                const int ch = (ks * 4 + l16) ^ (row & 7);
                bb[n][ks] = *(const bf16x8*)&sl[row * 64 + ch * 8];
            }
        }
    };
    auto mm16 = [&](int mh, int pair, bf16x8 (&bb)[2][2]) {
        __builtin_amdgcn_s_setprio(1);
#pragma unroll
        for (int ks = 0; ks < 2; ++ks)
#pragma unroll
            for (int m = 0; m < 4; ++m)
#pragma unroll
                for (int n = 0; n < 2; ++n)
                    acc[mh * 4 + m][pair * 2 + n] =
                        __builtin_amdgcn_mfma_f32_16x16x32_bf16(af[m][ks], bb[n][ks],
                                                                acc[mh * 4 + m][pair * 2 + n], 0, 0, 0);
        __builtin_amdgcn_s_setprio(0);
    };

    const int nt = K >> 6;
    stage(&As[0][0], Ab, 0);
    stage(&Bs[0][0], Bb, 0);
    stage(&As[1][0], Ab, 64);

    for (int t = 0; t < nt; ++t) {
        u16* Asl = &As[t & 1][0];
        u16* Bsl = &Bs[t & 1][0];
        u16* Aso = &As[t & 1][0];
        u16* Bso = &Bs[(t + 1) & 1][0];

        if (t + 1 < nt) { asm volatile("s_waitcnt vmcnt(4)" ::: "memory"); }
        else            { asm volatile("s_waitcnt vmcnt(0)" ::: "memory"); }
        __builtin_amdgcn_s_barrier();
        ldAf(Asl, 0);
        ldBf(Bsl, 0, bbA);
        if (t + 1 < nt) stage(Bso, Bb, (t + 1) * 64);
        __builtin_amdgcn_s_barrier();
        mm16(0, 0, bbA);
        __builtin_amdgcn_s_barrier();
        ldBf(Bsl, 1, bbB);
        mm16(0, 1, bbB);
        __builtin_amdgcn_s_barrier();
        ldAf(Asl, 1);
        mm16(1, 0, bbA);
        __builtin_amdgcn_s_barrier();
        if (t + 2 < nt) stage(Aso, Ab, (t + 2) * 64);
        mm16(1, 1, bbB);
        __builtin_amdgcn_s_barrier();
    }

#pragma unroll
    for (int n = 0; n < 4; ++n) {
        const int col = c0 + wc * 64 + n * 16 + l15;
        const float bv = bias[col];
#pragma unroll
        for (int m = 0; m < 8; ++m) {
#pragma unroll
            for (int r = 0; r < 4; ++r) {
                const size_t row = (size_t)(r0 + wr * 128 + m * 16 + l16 * 4 + r);
                float v = acc[m][n][r] + bv;
                if (RELU) v = fmaxf(v, 0.f);
                C[row * N + col] = f2bf(v);
            }
        }
    }
}

// ---------------------------------------------------------------------------
// Pipelined 128x128 GEMM (counted-vmcnt, 2 barriers/K-tile, dbuf LDS).
// 512 thr = 8 waves (2M x 4N), wave tile 64x32. For N=1024 GEMMs (grid 256).
// ---------------------------------------------------------------------------
template<int RELU>
__global__ __launch_bounds__(512, 2)
void gemm_pipe128(const u16* __restrict__ A, const u16* __restrict__ Bt,
                  const float* __restrict__ bias, u16* __restrict__ C,
                  int M, int N, int K)
{
    __shared__ u16 As[2][128 * 64];
    __shared__ u16 Bs[2][128 * 64];

    const int tid = threadIdx.x;
    const int wid = tid >> 6, lane = tid & 63;
    const int wr  = wid >> 2, wc = wid & 3;
    const int l15 = lane & 15, l16 = lane >> 4;

    const int nwg = gridDim.x * gridDim.y;          // multiple of 8
    int bid = blockIdx.y * gridDim.x + blockIdx.x;
    bid = (bid & 7) * (nwg >> 3) + (bid >> 3);
    const int r0 = (bid / gridDim.x) * 128, c0 = (bid % gridDim.x) * 128;

    const u16* Ab = A  + (size_t)r0 * K;
    const u16* Bb = Bt + (size_t)c0 * K;

    f32x4 acc[4][2];
#pragma unroll
    for (int m = 0; m < 4; ++m)
#pragma unroll
        for (int n = 0; n < 2; ++n) acc[m][n] = (f32x4){0.f, 0.f, 0.f, 0.f};

    auto stage = [&](u16* dst, const u16* src, int kbase) {
#pragma unroll
        for (int i = 0; i < 2; ++i) {
            const int r  = i * 64 + (tid >> 3);
            const int gc = (tid & 7) ^ (r & 7);
            __builtin_amdgcn_global_load_lds(AS1C(src + (size_t)r * K + kbase + gc * 8),
                                             AS3(dst + (i * 64 + (wid << 3)) * 64), 16, 0, 0);
        }
    };

    const int nt = K >> 6;
    stage(&As[0][0], Ab, 0);  stage(&Bs[0][0], Bb, 0);
    stage(&As[1][0], Ab, 64); stage(&Bs[1][0], Bb, 64);

    for (int t = 0; t < nt; ++t) {
        const u16* Asl = &As[t & 1][0];
        const u16* Bsl = &Bs[t & 1][0];

        if (t + 1 < nt) { asm volatile("s_waitcnt vmcnt(4)" ::: "memory"); }
        else            { asm volatile("s_waitcnt vmcnt(0)" ::: "memory"); }
        __builtin_amdgcn_s_barrier();

        bf16x8 af[4][2], bb[2][2];
#pragma unroll
        for (int m = 0; m < 4; ++m) {
            const int row = wr * 64 + m * 16 + l15;
#pragma unroll
            for (int ks = 0; ks < 2; ++ks) {
                const int ch = (ks * 4 + l16) ^ (row & 7);
                af[m][ks] = *(const bf16x8*)&Asl[row * 64 + ch * 8];
            }
        }
#pragma unroll
        for (int n = 0; n < 2; ++n) {
            const int row = wc * 32 + n * 16 + l15;
#pragma unroll
            for (int ks = 0; ks < 2; ++ks) {
                const int ch = (ks * 4 + l16) ^ (row & 7);
                bb[n][ks] = *(const bf16x8*)&Bsl[row * 64 + ch * 8];
            }
        }
        __builtin_amdgcn_s_setprio(1);
#pragma unroll
        for (int ks = 0; ks < 2; ++ks)
#pragma unroll
            for (int m = 0; m < 4; ++m)
#pragma unroll
                for (int n = 0; n < 2; ++n)
                    acc[m][n] = __builtin_amdgcn_mfma_f32_16x16x32_bf16(af[m][ks], bb[n][ks], acc[m][n], 0, 0, 0);
        __builtin_amdgcn_s_setprio(0);
        __builtin_amdgcn_s_barrier();

        if (t + 2 < nt) {
            stage(&As[t & 1][0], Ab, (t + 2) * 64);
            stage(&Bs[t & 1][0], Bb, (t + 2) * 64);
        }
    }

#pragma unroll
    for (int n = 0; n < 2; ++n) {
        const int col = c0 + wc * 32 + n * 16 + l15;
        const float bv = bias[col];
#pragma unroll
        for (int m = 0; m < 4; ++m) {
#pragma unroll
            for (int r = 0; r < 4; ++r) {
                const size_t row = (size_t)(r0 + wr * 64 + m * 16 + l16 * 4 + r);
                float v = acc[m][n][r] + bv;
                if (RELU) v = fmaxf(v, 0.f);
                C[row * N + col] = f2bf(v);
            }
        }
    }
}

// ---------------------------------------------------------------------------
// MFMA flash attention v5: 8 waves (512 thr), 128 q-rows/block (16/wave),
// swapped QK^T (lane-local P), zero-shuffle PV, base-2 softmax + defer-max.
// K/V staged once per tile, shared by 8 waves.
// ---------------------------------------------------------------------------
__global__ __launch_bounds__(512, 4)
void attn_mfma(const u16* __restrict__ qkv, u16* __restrict__ ao)
{
    __shared__ u16 Kl[64 * 64];       // [s][d] bf16, chunk^(s&7) swizzle
    __shared__ u32 Vt[64 * 32];       // [d][s/2] packed (s even, s odd)

    const int tid = threadIdx.x;
    const int wid = tid >> 6, lane = tid & 63;
    const int l15 = lane & 15, l16 = lane >> 4;
    const int bh  = blockIdx.y, b = bh >> 4, h = bh & 15;
    const int ho  = h * 64;
    const size_t tb = (size_t)b * SEQ_L;
    const int q0  = blockIdx.x * 128;

    const u16* qg = qkv + (tb + q0) * 3072 + ho;
    const u16* kg = qkv + tb * 3072 + 1024 + ho;
    const u16* vg = qkv + tb * 3072 + 2048 + ho;

    const float SC = 0.18033688f;     // (1/8) * log2(e)

    // Q fragments, pre-scaled by SC: q-row = wid*16 + l15
    bf16x8 qa[2];
#pragma unroll
    for (int ks = 0; ks < 2; ++ks) {
        union { bf16x8 v; u16 u[8]; u32 w[4]; } a, r;
        a.v = *(const bf16x8*)(qg + (size_t)(wid * 16 + l15) * 3072 + ks * 32 + l16 * 8);
#pragma unroll
        for (int e = 0; e < 4; ++e)
            r.w[e] = cvt_pk_bf16(bf2f(a.u[2 * e]) * SC, bf2f(a.u[2 * e + 1]) * SC);
        qa[ks] = r.v;
    }

    // V staging assignment: 512 thr -> pair sp = tid&31, d-chunk dc = tid>>5
    const int sp = tid & 31;
    const int dc = tid >> 5;

    f32x4 oacc[4];
#pragma unroll
    for (int f = 0; f < 4; ++f) oacc[f] = (f32x4){0.f, 0.f, 0.f, 0.f};
    float m_c = -1e30f, l_c = 0.f;

    for (int s0 = 0; s0 < SEQ_L; s0 += 64) {
        // V loads issued early
        ushort4 ua4 = *(const ushort4*)(vg + (size_t)(s0 + 2 * sp) * 3072 + dc * 4);
        ushort4 ub4 = *(const ushort4*)(vg + (size_t)(s0 + 2 * sp + 1) * 3072 + dc * 4);

        __syncthreads();
        // K tile: one gload_lds per thread (wave w covers rows w*8..w*8+7)
        {
            const int r  = tid >> 3;
            const int gc = (tid & 7) ^ (r & 7);
            __builtin_amdgcn_global_load_lds(AS1C(kg + (size_t)(s0 + r) * 3072 + gc * 8),
                                             AS3(&Kl[(wid * 8) * 64]), 16, 0, 0);
        }
        // V: packed pairs, swizzled dword index
        {
            const u16* pu = (const u16*)&ua4;
            const u16* pv = (const u16*)&ub4;
#pragma unroll
            for (int e = 0; e < 4; ++e) {
                const int d = dc * 4 + e;
                const int w = sp ^ (((d & 7) << 2) ^ ((d >> 3) << 1));
                Vt[d * 32 + w] = (u32)pu[e] | ((u32)pv[e] << 16);
            }
        }
        __syncthreads();

        // S^T = K Q^T : sacc[f][r] = S[s = f*16 + l16*4 + r][q = l15]
        f32x4 sacc[4];
#pragma unroll
        for (int f = 0; f < 4; ++f) sacc[f] = (f32x4){0.f, 0.f, 0.f, 0.f};
#pragma unroll
        for (int ks = 0; ks < 2; ++ks)
#pragma unroll
            for (int f = 0; f < 4; ++f) {
                const int row = f * 16 + l15;
                const int ch  = (ks * 4 + l16) ^ (row & 7);
                bf16x8 kb = *(const bf16x8*)&Kl[row * 64 + ch * 8];
                sacc[f] = __builtin_amdgcn_mfma_f32_16x16x32_bf16(kb, qa[ks], sacc[f], 0, 0, 0);
            }

        // per-lane max over 16 held s-values (v_max3 tree), then 2 shfl
        float mx;
        {
            float a0 = fmax3(sacc[0][0], sacc[0][1], sacc[0][2]);
            float a1 = fmax3(sacc[0][3], sacc[1][0], sacc[1][1]);
            float a2 = fmax3(sacc[1][2], sacc[1][3], sacc[2][0]);
            float a3 = fmax3(sacc[2][1], sacc[2][2], sacc[2][3]);
            float a4 = fmax3(sacc[3][0], sacc[3][1], sacc[3][2]);
            float b0 = fmax3(a0, a1, sacc[3][3]);
            float b1 = fmax3(a2, a3, a4);
            mx = fmaxf(b0, b1);
        }
        mx = fmaxf(mx, __shfl_xor(mx, 16));
        mx = fmaxf(mx, __shfl_xor(mx, 32));

        if (__any(mx > m_c + 8.f)) {                 // defer-max
            const float mnew = fmaxf(m_c, mx);
            const float corr = __builtin_exp2f(m_c - mnew);
            m_c = mnew;
            l_c *= corr;
#pragma unroll
            for (int r = 0; r < 4; ++r) {
                const float cr = __shfl(corr, l16 * 4 + r);
#pragma unroll
                for (int f = 0; f < 4; ++f) oacc[f][r] *= cr;
            }
        }

        float rs = 0.f;
#pragma unroll
        for (int f = 0; f < 4; ++f)
#pragma unroll
            for (int r = 0; r < 4; ++r) {
                const float p = __builtin_exp2f(sacc[f][r] - m_c);
                sacc[f][r] = p; rs += p;
            }
        rs += __shfl_xor(rs, 16);
        rs += __shfl_xor(rs, 32);
        l_c += rs;

        // pack P to bf16 pairs
        u32 pk[4][2];
#pragma unroll
        for (int f = 0; f < 4; ++f) {
            pk[f][0] = cvt_pk_bf16(sacc[f][0], sacc[f][1]);
            pk[f][1] = cvt_pk_bf16(sacc[f][2], sacc[f][3]);
        }

        // O += P V with k-order sigma(l16,j) = 32S + (j>>2)*16 + l16*4 + (j&3)
#pragma unroll
        for (int S = 0; S < 2; ++S) {
            union { bf16x8 v; u32 u[4]; } af;
            af.u[0] = pk[2 * S][0];     af.u[1] = pk[2 * S][1];
            af.u[2] = pk[2 * S + 1][0]; af.u[3] = pk[2 * S + 1][1];
#pragma unroll
            for (int f2 = 0; f2 < 4; ++f2) {
                const int d = f2 * 16 + l15;
                const int swzd = ((d & 7) << 2) ^ ((d >> 3) << 1);
                union { bf16x8 v; uint2 u[2]; } vb;
                vb.u[0] = *(const uint2*)&Vt[d * 32 + ((16 * S + 2 * l16) ^ swzd)];
                vb.u[1] = *(const uint2*)&Vt[d * 32 + ((16 * S + 8 + 2 * l16) ^ swzd)];
                oacc[f2] = __builtin_amdgcn_mfma_f32_16x16x32_bf16(af.v, vb.v, oacc[f2], 0, 0, 0);
            }
        }
    }

    // epilogue: O rows q = l16*4 + r, cols d = f2*16 + l15
#pragma unroll
    for (int r = 0; r < 4; ++r) {
        const float ld  = __shfl(l_c, l16 * 4 + r);
        const float inv = 1.f / ld;
        const size_t row = tb + q0 + wid * 16 + l16 * 4 + r;
#pragma unroll
        for (int f2 = 0; f2 < 4; ++f2)
            ao[row * 1024 + ho + f2 * 16 + l15] = f2bf(oacc[f2][r] * inv);
    }
}

// ---------------------------------------------------------------------------
// out_f32 = LN(x_f32 + y_bf16); optionally also bf16 copy.
// ---------------------------------------------------------------------------
template<int WB>
__global__ __launch_bounds__(256)
void add_ln(const float* __restrict__ x, const u16* __restrict__ y,
            const float* __restrict__ g, const float* __restrict__ be,
            float* __restrict__ outf, u16* __restrict__ outb)
{
    __shared__ float red[4];
    const int t = blockIdx.x, tid = threadIdx.x;
    const int c = tid * 4, lane = tid & 63, wv = tid >> 6;

    float4 a = *(const float4*)(x + (size_t)t * D_MODEL + c);
    ushort4 yb = *(const ushort4*)(y + (size_t)t * D_MODEL + c);
    float s[4] = {a.x + bf2f(yb.x), a.y + bf2f(yb.y), a.z + bf2f(yb.z), a.w + bf2f(yb.w)};

    float ps = s[0] + s[1] + s[2] + s[3];
#pragma unroll
    for (int off = 32; off > 0; off >>= 1) ps += __shfl_down(ps, off);
    if (lane == 0) red[wv] = ps;
    __syncthreads();
    const float mean = (red[0] + red[1] + red[2] + red[3]) * (1.f / D_MODEL);
    __syncthreads();

    float pv = 0.f;
#pragma unroll
    for (int u = 0; u < 4; ++u) { float d = s[u] - mean; pv += d * d; }
#pragma unroll
    for (int off = 32; off > 0; off >>= 1) pv += __shfl_down(pv, off);
    if (lane == 0) red[wv] = pv;
    __syncthreads();
    const float var = (red[0] + red[1] + red[2] + red[3]) * (1.f / D_MODEL);
    const float inv = rsqrtf(var + 1e-5f);

    float4 g4 = *(const float4*)(g + c);
    float4 b4 = *(const float4*)(be + c);
    float o[4];
#pragma unroll
    for (int u = 0; u < 4; ++u) o[u] = (s[u] - mean) * inv;
    float4 of = {o[0] * g4.x + b4.x, o[1] * g4.y + b4.y, o[2] * g4.z + b4.z, o[3] * g4.w + b4.w};
    *(float4*)(outf + (size_t)t * D_MODEL + c) = of;
    if (WB) {
        ushort4 ob = {f2bf(of.x), f2bf(of.y), f2bf(of.z), f2bf(of.w)};
        *(ushort4*)(outb + (size_t)t * D_MODEL + c) = ob;
    }
}

// ---------------------------------------------------------------------------
// Merged preprocessing (unchanged).
// ---------------------------------------------------------------------------
__global__ __launch_bounds__(256)
void prep(const float* __restrict__ Wq, const float* __restrict__ Wk,
          const float* __restrict__ Wv, const float* __restrict__ Wm,
          const float* __restrict__ W1, const float* __restrict__ W2,
          const float* __restrict__ x,
          const float* __restrict__ bq, const float* __restrict__ bk,
          const float* __restrict__ bv,
          u16* __restrict__ wqkv_t, u16* __restrict__ wm_t,
          u16* __restrict__ w1_t, u16* __restrict__ w2_t,
          u16* __restrict__ xb, float* __restrict__ bqkv)
{
    const int blk = blockIdx.x, tid = threadIdx.x;
    if (blk < 3072) {
        __shared__ float T[64][65];
        const float* src; u16* dst; int K, N, tile;
        if (blk < 256)       { src = Wq; dst = wqkv_t;               K = 1024; N = 1024; tile = blk; }
        else if (blk < 512)  { src = Wk; dst = wqkv_t + 1024 * 1024; K = 1024; N = 1024; tile = blk - 256; }
        else if (blk < 768)  { src = Wv; dst = wqkv_t + 2*1024*1024; K = 1024; N = 1024; tile = blk - 512; }
        else if (blk < 1024) { src = Wm; dst = wm_t;                 K = 1024; N = 1024; tile = blk - 768; }
        else if (blk < 2048) { src = W1; dst = w1_t;                 K = 1024; N = 4096; tile = blk - 1024; }
        else                 { src = W2; dst = w2_t;                 K = 4096; N = 1024; tile = blk - 2048; }
        const int ntn = N >> 6;
        const int n0 = (tile % ntn) * 64, k0 = (tile / ntn) * 64;
        const int rr = tid >> 4, cc = (tid & 15) * 4;
#pragma unroll
        for (int u = 0; u < 4; ++u) {
            const float4 v = *(const float4*)(src + (size_t)(k0 + rr + u * 16) * N + n0 + cc);
            T[rr + u * 16][cc + 0] = v.x; T[rr + u * 16][cc + 1] = v.y;
            T[rr + u * 16][cc + 2] = v.z; T[rr + u * 16][cc + 3] = v.w;
        }
        __syncthreads();
#pragma unroll
        for (int u = 0; u < 4; ++u) {
            const int n = rr + u * 16;
            ushort4 o;
            o.x = f2bf(T[cc + 0][n]); o.y = f2bf(T[cc + 1][n]);
            o.z = f2bf(T[cc + 2][n]); o.w = f2bf(T[cc + 3][n]);
            *(ushort4*)(dst + (size_t)(n0 + n) * K + k0 + cc) = o;
        }
    } else if (blk < 3072 + 4096) {
        const int i = (blk - 3072) * 1024 + tid * 4;
        float4 v = *(const float4*)(x + i);
        ushort4 o = {f2bf(v.x), f2bf(v.y), f2bf(v.z), f2bf(v.w)};
        *(ushort4*)(xb + i) = o;
    } else {
#pragma unroll
        for (int u = 0; u < 12; ++u) {
            const int i = u * 256 + tid;
            bqkv[i] = i < 1024 ? bq[i] : (i < 2048 ? bk[i - 1024] : bv[i - 2048]);
        }
    }
}

// ---------------------------------------------------------------------------
extern "C" void kernel_launch(void* const* d_in, const int* in_sizes, int n_in,
                              void* d_out, int out_size, void* d_ws, size_t ws_size,
                              hipStream_t stream)
{
    (void)in_sizes; (void)n_in; (void)out_size; (void)ws_size;

    const float* x   = (const float*)d_in[0];
    const float* Wq  = (const float*)d_in[1];
    const float* bq  = (const float*)d_in[2];
    const float* Wk  = (const float*)d_in[3];
    const float* bk  = (const float*)d_in[4];
    const float* Wv  = (const float*)d_in[5];
    const float* bv  = (const float*)d_in[6];
    const float* Wm  = (const float*)d_in[7];
    const float* bm  = (const float*)d_in[8];
    const float* W1  = (const float*)d_in[9];
    const float* b1  = (const float*)d_in[10];
    const float* W2  = (const float*)d_in[11];
    const float* b2  = (const float*)d_in[12];
    const float* g1  = (const float*)d_in[13];
    const float* be1 = (const float*)d_in[14];
    const float* g2  = (const float*)d_in[15];
    const float* be2 = (const float*)d_in[16];
    float* out = (float*)d_out;

    char* base = (char*)d_ws;
    const size_t MB = 1u << 20;
    u16*   wqkv_t = (u16*)(base);              //  0..6MB : [3072][1024]
    u16*   wm_t   = (u16*)(base + 6 * MB);     //  6..8MB
    u16*   w1_t   = (u16*)(base + 8 * MB);     //  8..16MB: [4096][1024]
    u16*   w2_t   = (u16*)(base + 16 * MB);    // 16..24MB: [1024][4096]
    float* bqkv   = (float*)(base + 24 * MB);
    u16*   xb     = (u16*)(base + 25 * MB);    // 25..33MB (dead after QKV)
    u16*   qkv    = (u16*)(base + 33 * MB);    // 33..57MB [4096][3072]
    u16*   ao     = (u16*)(base + 57 * MB);    // 57..65MB
    u16*   f1     = (u16*)(base + 33 * MB);    // alias qkv+ao
    u16*   msg    = (u16*)(base + 25 * MB);    // alias xb
    u16*   ffn    = (u16*)(base + 25 * MB);
    float* hf     = (float*)(base + 65 * MB);
    u16*   hb     = (u16*)(base + 81 * MB);

    dim3 blk(256);
    prep<<<dim3(3072 + 4096 + 1), blk, 0, stream>>>(Wq, Wk, Wv, Wm, W1, W2, x,
                                                    bq, bk, bv,
                                                    wqkv_t, wm_t, w1_t, w2_t, xb, bqkv);

    gemm_pipe<0><<<dim3(12, 16), dim3(512), 0, stream>>>(xb, wqkv_t, bqkv, qkv, N_TOK, 3072, 1024);
    attn_mfma<<<dim3(SEQ_L / 128, 32), dim3(512), 0, stream>>>(qkv, ao);
    gemm_pipe128<0><<<dim3(8, 32), dim3(512), 0, stream>>>(ao, wm_t, bm, msg, N_TOK, 1024, 1024);
    add_ln<1><<<dim3(N_TOK), blk, 0, stream>>>(x, msg, g1, be1, hf, hb);
    gemm_pipe<1><<<dim3(16, 16), dim3(512), 0, stream>>>(hb, w1_t, b1, f1, N_TOK, FF_DIM, 1024);
    gemm_pipe128<0><<<dim3(8, 32), dim3(512), 0, stream>>>(f1, w2_t, b2, ffn, N_TOK, 1024, FF_DIM);
    add_ln<0><<<dim3(N_TOK), blk, 0, stream>>>(hf, ffn, g2, be2, out, nullptr);
}

// Round 6
// 256.183 us; speedup vs baseline: 7.8124x; 1.0072x over previous
//
#include <hip/hip_runtime.h>

#define D_MODEL 1024
#define N_TOK   4096
#define HEADS   16
#define FF_DIM  4096
#define SEQ_L   2048

typedef unsigned short u16;
typedef unsigned int   u32;
typedef __bf16 bf16x8 __attribute__((ext_vector_type(8)));
typedef float  f32x4  __attribute__((ext_vector_type(4)));

#define AS1C(p) ((const __attribute__((address_space(1))) void*)(p))
#define AS3(p)  ((__attribute__((address_space(3))) void*)(p))

__device__ __forceinline__ u16 f2bf(float f) {
    union { float f; unsigned u; } c; c.f = f;
    return (u16)((c.u + 0x7fffu + ((c.u >> 16) & 1u)) >> 16);   // RNE
}
__device__ __forceinline__ float bf2f(u16 b) {
    union { unsigned u; float f; } c; c.u = ((unsigned)b) << 16;
    return c.f;
}
__device__ __forceinline__ u32 cvt_pk_bf16(float lo, float hi) {
    u32 r;
    asm("v_cvt_pk_bf16_f32 %0, %1, %2" : "=v"(r) : "v"(lo), "v"(hi));
    return r;
}
__device__ __forceinline__ float fmax3(float a, float b, float c) {
    float r;
    asm("v_max3_f32 %0, %1, %2, %3" : "=v"(r) : "v"(a), "v"(b), "v"(c));
    return r;
}

// ---------------------------------------------------------------------------
// Pipelined 256x256 GEMM (counted-vmcnt, 4 phases/K-tile, double-buffer LDS).
// ---------------------------------------------------------------------------
template<int RELU>
__global__ __launch_bounds__(512, 2)
void gemm_pipe(const u16* __restrict__ A, const u16* __restrict__ Bt,
               const float* __restrict__ bias, u16* __restrict__ C,
               int M, int N, int K)
{
    __shared__ u16 As[2][256 * 64];
    __shared__ u16 Bs[2][256 * 64];

    const int tid = threadIdx.x;
    const int wid = tid >> 6, lane = tid & 63;
    const int wr  = wid >> 2, wc = wid & 3;
    const int l15 = lane & 15, l16 = lane >> 4;

    const int nwg = gridDim.x * gridDim.y;
    int bid = blockIdx.y * gridDim.x + blockIdx.x;
    bid = (bid & 7) * (nwg >> 3) + (bid >> 3);
    const int r0 = (bid / gridDim.x) * 256, c0 = (bid % gridDim.x) * 256;

    const u16* Ab = A  + (size_t)r0 * K;
    const u16* Bb = Bt + (size_t)c0 * K;

    f32x4 acc[8][4];
#pragma unroll
    for (int m = 0; m < 8; ++m)
#pragma unroll
        for (int n = 0; n < 4; ++n) acc[m][n] = (f32x4){0.f, 0.f, 0.f, 0.f};

    auto stage = [&](u16* dst, const u16* src, int kbase) {
#pragma unroll
        for (int i = 0; i < 4; ++i) {
            const int r  = i * 64 + (tid >> 3);
            const int gc = (tid & 7) ^ (r & 7);
            __builtin_amdgcn_global_load_lds(AS1C(src + (size_t)r * K + kbase + gc * 8),
                                             AS3(dst + (i * 64 + (wid << 3)) * 64), 16, 0, 0);
        }
    };

    bf16x8 af[4][2], bbA[2][2], bbB[2][2];

    auto ldAf = [&](const u16* sl, int mh) {
#pragma unroll
        for (int m = 0; m < 4; ++m) {
            const int row = wr * 128 + (mh * 4 + m) * 16 + l15;
#pragma unroll
            for (int ks = 0; ks < 2; ++ks) {
                const int ch = (ks * 4 + l16) ^ (row & 7);
                af[m][ks] = *(const bf16x8*)&sl[row * 64 + ch * 8];
            }
        }
    };
    auto ldBf = [&](const u16* sl, int pair, bf16x8 (&bb)[2][2]) {
#pragma unroll
        for (int n = 0; n < 2; ++n) {
            const int row = wc * 64 + (pair * 2 + n) * 16 + l15;
#pragma unroll
            for (int ks = 0; ks < 2; ++ks) {
                const int ch = (ks * 4 + l16) ^ (row & 7);
                bb[n][ks] = *(const bf16x8*)&sl[row * 64 + ch * 8];
            }
        }
    };
    auto mm16 = [&](int mh, int pair, bf16x8 (&bb)[2][2]) {
        __builtin_amdgcn_s_setprio(1);
#pragma unroll
        for (int ks = 0; ks < 2; ++ks)
#pragma unroll
            for (int m = 0; m < 4; ++m)
#pragma unroll
                for (int n = 0; n < 2; ++n)
                    acc[mh * 4 + m][pair * 2 + n] =
                        __builtin_amdgcn_mfma_f32_16x16x32_bf16(af[m][ks], bb[n][ks],
                                                                acc[mh * 4 + m][pair * 2 + n], 0, 0, 0);
        __builtin_amdgcn_s_setprio(0);
    };

    const int nt = K >> 6;
    stage(&As[0][0], Ab, 0);
    stage(&Bs[0][0], Bb, 0);
    stage(&As[1][0], Ab, 64);

    for (int t = 0; t < nt; ++t) {
        u16* Asl = &As[t & 1][0];
        u16* Bsl = &Bs[t & 1][0];
        u16* Aso = &As[t & 1][0];
        u16* Bso = &Bs[(t + 1) & 1][0];

        if (t + 1 < nt) { asm volatile("s_waitcnt vmcnt(4)" ::: "memory"); }
        else            { asm volatile("s_waitcnt vmcnt(0)" ::: "memory"); }
        __builtin_amdgcn_s_barrier();
        ldAf(Asl, 0);
        ldBf(Bsl, 0, bbA);
        if (t + 1 < nt) stage(Bso, Bb, (t + 1) * 64);
        __builtin_amdgcn_s_barrier();
        mm16(0, 0, bbA);
        __builtin_amdgcn_s_barrier();
        ldBf(Bsl, 1, bbB);
        mm16(0, 1, bbB);
        __builtin_amdgcn_s_barrier();
        ldAf(Asl, 1);
        mm16(1, 0, bbA);
        __builtin_amdgcn_s_barrier();
        if (t + 2 < nt) stage(Aso, Ab, (t + 2) * 64);
        mm16(1, 1, bbB);
        __builtin_amdgcn_s_barrier();
    }

#pragma unroll
    for (int n = 0; n < 4; ++n) {
        const int col = c0 + wc * 64 + n * 16 + l15;
        const float bv = bias[col];
#pragma unroll
        for (int m = 0; m < 8; ++m) {
#pragma unroll
            for (int r = 0; r < 4; ++r) {
                const size_t row = (size_t)(r0 + wr * 128 + m * 16 + l16 * 4 + r);
                float v = acc[m][n][r] + bv;
                if (RELU) v = fmaxf(v, 0.f);
                C[row * N + col] = f2bf(v);
            }
        }
    }
}

// ---------------------------------------------------------------------------
// Pipelined 128x128 GEMM (counted-vmcnt, 2 barriers/K-tile, dbuf LDS).
// ---------------------------------------------------------------------------
template<int RELU>
__global__ __launch_bounds__(512, 2)
void gemm_pipe128(const u16* __restrict__ A, const u16* __restrict__ Bt,
                  const float* __restrict__ bias, u16* __restrict__ C,
                  int M, int N, int K)
{
    __shared__ u16 As[2][128 * 64];
    __shared__ u16 Bs[2][128 * 64];

    const int tid = threadIdx.x;
    const int wid = tid >> 6, lane = tid & 63;
    const int wr  = wid >> 2, wc = wid & 3;
    const int l15 = lane & 15, l16 = lane >> 4;

    const int nwg = gridDim.x * gridDim.y;
    int bid = blockIdx.y * gridDim.x + blockIdx.x;
    bid = (bid & 7) * (nwg >> 3) + (bid >> 3);
    const int r0 = (bid / gridDim.x) * 128, c0 = (bid % gridDim.x) * 128;

    const u16* Ab = A  + (size_t)r0 * K;
    const u16* Bb = Bt + (size_t)c0 * K;

    f32x4 acc[4][2];
#pragma unroll
    for (int m = 0; m < 4; ++m)
#pragma unroll
        for (int n = 0; n < 2; ++n) acc[m][n] = (f32x4){0.f, 0.f, 0.f, 0.f};

    auto stage = [&](u16* dst, const u16* src, int kbase) {
#pragma unroll
        for (int i = 0; i < 2; ++i) {
            const int r  = i * 64 + (tid >> 3);
            const int gc = (tid & 7) ^ (r & 7);
            __builtin_amdgcn_global_load_lds(AS1C(src + (size_t)r * K + kbase + gc * 8),
                                             AS3(dst + (i * 64 + (wid << 3)) * 64), 16, 0, 0);
        }
    };

    const int nt = K >> 6;
    stage(&As[0][0], Ab, 0);  stage(&Bs[0][0], Bb, 0);
    stage(&As[1][0], Ab, 64); stage(&Bs[1][0], Bb, 64);

    for (int t = 0; t < nt; ++t) {
        const u16* Asl = &As[t & 1][0];
        const u16* Bsl = &Bs[t & 1][0];

        if (t + 1 < nt) { asm volatile("s_waitcnt vmcnt(4)" ::: "memory"); }
        else            { asm volatile("s_waitcnt vmcnt(0)" ::: "memory"); }
        __builtin_amdgcn_s_barrier();

        bf16x8 af[4][2], bb[2][2];
#pragma unroll
        for (int m = 0; m < 4; ++m) {
            const int row = wr * 64 + m * 16 + l15;
#pragma unroll
            for (int ks = 0; ks < 2; ++ks) {
                const int ch = (ks * 4 + l16) ^ (row & 7);
                af[m][ks] = *(const bf16x8*)&Asl[row * 64 + ch * 8];
            }
        }
#pragma unroll
        for (int n = 0; n < 2; ++n) {
            const int row = wc * 32 + n * 16 + l15;
#pragma unroll
            for (int ks = 0; ks < 2; ++ks) {
                const int ch = (ks * 4 + l16) ^ (row & 7);
                bb[n][ks] = *(const bf16x8*)&Bsl[row * 64 + ch * 8];
            }
        }
        __builtin_amdgcn_s_setprio(1);
#pragma unroll
        for (int ks = 0; ks < 2; ++ks)
#pragma unroll
            for (int m = 0; m < 4; ++m)
#pragma unroll
                for (int n = 0; n < 2; ++n)
                    acc[m][n] = __builtin_amdgcn_mfma_f32_16x16x32_bf16(af[m][ks], bb[n][ks], acc[m][n], 0, 0, 0);
        __builtin_amdgcn_s_setprio(0);
        __builtin_amdgcn_s_barrier();

        if (t + 2 < nt) {
            stage(&As[t & 1][0], Ab, (t + 2) * 64);
            stage(&Bs[t & 1][0], Bb, (t + 2) * 64);
        }
    }

#pragma unroll
    for (int n = 0; n < 2; ++n) {
        const int col = c0 + wc * 32 + n * 16 + l15;
        const float bv = bias[col];
#pragma unroll
        for (int m = 0; m < 4; ++m) {
#pragma unroll
            for (int r = 0; r < 4; ++r) {
                const size_t row = (size_t)(r0 + wr * 64 + m * 16 + l16 * 4 + r);
                float v = acc[m][n][r] + bv;
                if (RELU) v = fmaxf(v, 0.f);
                C[row * N + col] = f2bf(v);
            }
        }
    }
}

// ---------------------------------------------------------------------------
// MFMA flash attention v6: 8 waves, 128 q-rows/block, KVBLK=128,
// double-buffered K (gload_lds prefetch), reg-staged V, XCD-chunked grid.
// ---------------------------------------------------------------------------
__global__ __launch_bounds__(512, 4)
void attn_mfma(const u16* __restrict__ qkv, u16* __restrict__ ao)
{
    __shared__ u16 Kl[2][128 * 64];   // [s][d] bf16, chunk^(s&7) swizzle
    __shared__ u32 Vt[64 * 64];       // [d][s/2] packed, word^mask(d) swizzle

    const int tid = threadIdx.x;
    const int wid = tid >> 6, lane = tid & 63;
    const int l15 = lane & 15, l16 = lane >> 4;

    // XCD-chunked decode: q-blocks of one head stay on one XCD
    int lin = blockIdx.y * gridDim.x + blockIdx.x;       // 512 blocks
    lin = (lin & 7) * 64 + (lin >> 3);
    const int bh = lin >> 4, b = bh >> 4, h = bh & 15;
    const int q0 = (lin & 15) * 128;
    const int ho = h * 64;
    const size_t tb = (size_t)b * SEQ_L;

    const u16* qg = qkv + (tb + q0) * 3072 + ho;
    const u16* kg = qkv + tb * 3072 + 1024 + ho;
    const u16* vg = qkv + tb * 3072 + 2048 + ho;

    const float SC = 0.18033688f;     // (1/8) * log2(e)

    // Q fragments, pre-scaled: q-row = wid*16 + l15
    bf16x8 qa[2];
#pragma unroll
    for (int ks = 0; ks < 2; ++ks) {
        union { bf16x8 v; u16 u[8]; u32 w[4]; } a, r;
        a.v = *(const bf16x8*)(qg + (size_t)(wid * 16 + l15) * 3072 + ks * 32 + l16 * 8);
#pragma unroll
        for (int e = 0; e < 4; ++e)
            r.w[e] = cvt_pk_bf16(bf2f(a.u[2 * e]) * SC, bf2f(a.u[2 * e + 1]) * SC);
        qa[ks] = r.v;
    }

    // V staging: pair sp = lane (s=2sp,2sp+1), d-chunk dc = wid (8 d's)
    const int sp = lane;
    const int dc = wid;

    auto stageK = [&](int buf, int s0) {
#pragma unroll
        for (int i = 0; i < 2; ++i) {
            const int r  = i * 64 + (tid >> 3);
            const int gc = (tid & 7) ^ (r & 7);
            __builtin_amdgcn_global_load_lds(AS1C(kg + (size_t)(s0 + r) * 3072 + gc * 8),
                                             AS3(&Kl[buf][(i * 64 + wid * 8) * 64]), 16, 0, 0);
        }
    };

    f32x4 oacc[4];
#pragma unroll
    for (int f = 0; f < 4; ++f) oacc[f] = (f32x4){0.f, 0.f, 0.f, 0.f};
    float m_c = -1e30f, l_c = 0.f;

    // prologue: K(0) -> Kl[0], V(0) -> regs
    union { bf16x8 v; u16 u[8]; } ua, ub;
    stageK(0, 0);
    ua.v = *(const bf16x8*)(vg + (size_t)(2 * sp) * 3072 + dc * 8);
    ub.v = *(const bf16x8*)(vg + (size_t)(2 * sp + 1) * 3072 + dc * 8);

    const int nt = SEQ_L / 128;
    for (int t = 0; t < nt; ++t) {
        const int buf = t & 1;

        asm volatile("s_waitcnt vmcnt(0)" ::: "memory");
        // write V(t) regs -> Vt (prev readers sealed by barrier-2 of t-1)
#pragma unroll
        for (int e = 0; e < 8; ++e) {
            const int d = dc * 8 + e;
            const int w = sp ^ (((d & 7) << 2) ^ ((d >> 3) << 1));
            Vt[d * 64 + w] = (u32)ua.u[e] | ((u32)ub.u[e] << 16);
        }
        __syncthreads();                               // barrier-1: K(t),V(t) visible

        if (t + 1 < nt) {                              // prefetch under compute
            stageK(buf ^ 1, (t + 1) * 128);
            ua.v = *(const bf16x8*)(vg + (size_t)((t + 1) * 128 + 2 * sp) * 3072 + dc * 8);
            ub.v = *(const bf16x8*)(vg + (size_t)((t + 1) * 128 + 2 * sp + 1) * 3072 + dc * 8);
        }

        // S^T = K Q^T : sacc[f][r] = S[s = f*16 + l16*4 + r][q = l15]
        f32x4 sacc[8];
#pragma unroll
        for (int f = 0; f < 8; ++f) sacc[f] = (f32x4){0.f, 0.f, 0.f, 0.f};
#pragma unroll
        for (int ks = 0; ks < 2; ++ks)
#pragma unroll
            for (int f = 0; f < 8; ++f) {
                const int row = f * 16 + l15;
                const int ch  = (ks * 4 + l16) ^ (row & 7);
                bf16x8 kb = *(const bf16x8*)&Kl[buf][row * 64 + ch * 8];
                sacc[f] = __builtin_amdgcn_mfma_f32_16x16x32_bf16(kb, qa[ks], sacc[f], 0, 0, 0);
            }

        // per-lane max over 32 held s-values, then 2 shfl
        float pm[8];
#pragma unroll
        for (int f = 0; f < 8; ++f)
            pm[f] = fmaxf(fmax3(sacc[f][0], sacc[f][1], sacc[f][2]), sacc[f][3]);
        float mx;
        {
            float t0 = fmax3(pm[0], pm[1], pm[2]);
            float t1 = fmax3(pm[3], pm[4], pm[5]);
            float t2 = fmaxf(pm[6], pm[7]);
            mx = fmax3(t0, t1, t2);
        }
        mx = fmaxf(mx, __shfl_xor(mx, 16));
        mx = fmaxf(mx, __shfl_xor(mx, 32));

        if (__any(mx > m_c + 8.f)) {                   // defer-max
            const float mnew = fmaxf(m_c, mx);
            const float corr = __builtin_exp2f(m_c - mnew);
            m_c = mnew;
            l_c *= corr;
#pragma unroll
            for (int r = 0; r < 4; ++r) {
                const float cr = __shfl(corr, l16 * 4 + r);
#pragma unroll
                for (int f = 0; f < 4; ++f) oacc[f][r] *= cr;
            }
        }

        float rs = 0.f;
#pragma unroll
        for (int f = 0; f < 8; ++f)
#pragma unroll
            for (int r = 0; r < 4; ++r) {
                const float p = __builtin_exp2f(sacc[f][r] - m_c);
                sacc[f][r] = p; rs += p;
            }
        rs += __shfl_xor(rs, 16);
        rs += __shfl_xor(rs, 32);
        l_c += rs;

        // pack P to bf16 pairs
        u32 pk[8][2];
#pragma unroll
        for (int f = 0; f < 8; ++f) {
            pk[f][0] = cvt_pk_bf16(sacc[f][0], sacc[f][1]);
            pk[f][1] = cvt_pk_bf16(sacc[f][2], sacc[f][3]);
        }

        // O += P V, k-order sigma: S in 0..3 over 128 s
#pragma unroll
        for (int S = 0; S < 4; ++S) {
            union { bf16x8 v; u32 u[4]; } af;
            af.u[0] = pk[2 * S][0];     af.u[1] = pk[2 * S][1];
            af.u[2] = pk[2 * S + 1][0]; af.u[3] = pk[2 * S + 1][1];
#pragma unroll
            for (int f2 = 0; f2 < 4; ++f2) {
                const int d = f2 * 16 + l15;
                const int swzd = ((d & 7) << 2) ^ ((d >> 3) << 1);
                union { bf16x8 v; uint2 u[2]; } vb;
                vb.u[0] = *(const uint2*)&Vt[d * 64 + ((16 * S + 2 * l16) ^ swzd)];
                vb.u[1] = *(const uint2*)&Vt[d * 64 + ((16 * S + 8 + 2 * l16) ^ swzd)];
                oacc[f2] = __builtin_amdgcn_mfma_f32_16x16x32_bf16(af.v, vb.v, oacc[f2], 0, 0, 0);
            }
        }
        __syncthreads();                               // barrier-2: tile consumed
    }

#pragma unroll
    for (int r = 0; r < 4; ++r) {
        const float ld  = __shfl(l_c, l16 * 4 + r);
        const float inv = 1.f / ld;
        const size_t row = tb + q0 + wid * 16 + l16 * 4 + r;
#pragma unroll
        for (int f2 = 0; f2 < 4; ++f2)
            ao[row * 1024 + ho + f2 * 16 + l15] = f2bf(oacc[f2][r] * inv);
    }
}

// ---------------------------------------------------------------------------
// out_f32 = LN(x_f32 + y_bf16); optionally also bf16 copy.
// ---------------------------------------------------------------------------
template<int WB>
__global__ __launch_bounds__(256)
void add_ln(const float* __restrict__ x, const u16* __restrict__ y,
            const float* __restrict__ g, const float* __restrict__ be,
            float* __restrict__ outf, u16* __restrict__ outb)
{
    __shared__ float red[4];
    const int t = blockIdx.x, tid = threadIdx.x;
    const int c = tid * 4, lane = tid & 63, wv = tid >> 6;

    float4 a = *(const float4*)(x + (size_t)t * D_MODEL + c);
    ushort4 yb = *(const ushort4*)(y + (size_t)t * D_MODEL + c);
    float s[4] = {a.x + bf2f(yb.x), a.y + bf2f(yb.y), a.z + bf2f(yb.z), a.w + bf2f(yb.w)};

    float ps = s[0] + s[1] + s[2] + s[3];
#pragma unroll
    for (int off = 32; off > 0; off >>= 1) ps += __shfl_down(ps, off);
    if (lane == 0) red[wv] = ps;
    __syncthreads();
    const float mean = (red[0] + red[1] + red[2] + red[3]) * (1.f / D_MODEL);
    __syncthreads();

    float pv = 0.f;
#pragma unroll
    for (int u = 0; u < 4; ++u) { float d = s[u] - mean; pv += d * d; }
#pragma unroll
    for (int off = 32; off > 0; off >>= 1) pv += __shfl_down(pv, off);
    if (lane == 0) red[wv] = pv;
    __syncthreads();
    const float var = (red[0] + red[1] + red[2] + red[3]) * (1.f / D_MODEL);
    const float inv = rsqrtf(var + 1e-5f);

    float4 g4 = *(const float4*)(g + c);
    float4 b4 = *(const float4*)(be + c);
    float o[4];
#pragma unroll
    for (int u = 0; u < 4; ++u) o[u] = (s[u] - mean) * inv;
    float4 of = {o[0] * g4.x + b4.x, o[1] * g4.y + b4.y, o[2] * g4.z + b4.z, o[3] * g4.w + b4.w};
    *(float4*)(outf + (size_t)t * D_MODEL + c) = of;
    if (WB) {
        ushort4 ob = {f2bf(of.x), f2bf(of.y), f2bf(of.z), f2bf(of.w)};
        *(ushort4*)(outb + (size_t)t * D_MODEL + c) = ob;
    }
}

// ---------------------------------------------------------------------------
// Merged preprocessing (unchanged).
// ---------------------------------------------------------------------------
__global__ __launch_bounds__(256)
void prep(const float* __restrict__ Wq, const float* __restrict__ Wk,
          const float* __restrict__ Wv, const float* __restrict__ Wm,
          const float* __restrict__ W1, const float* __restrict__ W2,
          const float* __restrict__ x,
          const float* __restrict__ bq, const float* __restrict__ bk,
          const float* __restrict__ bv,
          u16* __restrict__ wqkv_t, u16* __restrict__ wm_t,
          u16* __restrict__ w1_t, u16* __restrict__ w2_t,
          u16* __restrict__ xb, float* __restrict__ bqkv)
{
    const int blk = blockIdx.x, tid = threadIdx.x;
    if (blk < 3072) {
        __shared__ float T[64][65];
        const float* src; u16* dst; int K, N, tile;
        if (blk < 256)       { src = Wq; dst = wqkv_t;               K = 1024; N = 1024; tile = blk; }
        else if (blk < 512)  { src = Wk; dst = wqkv_t + 1024 * 1024; K = 1024; N = 1024; tile = blk - 256; }
        else if (blk < 768)  { src = Wv; dst = wqkv_t + 2*1024*1024; K = 1024; N = 1024; tile = blk - 512; }
        else if (blk < 1024) { src = Wm; dst = wm_t;                 K = 1024; N = 1024; tile = blk - 768; }
        else if (blk < 2048) { src = W1; dst = w1_t;                 K = 1024; N = 4096; tile = blk - 1024; }
        else                 { src = W2; dst = w2_t;                 K = 4096; N = 1024; tile = blk - 2048; }
        const int ntn = N >> 6;
        const int n0 = (tile % ntn) * 64, k0 = (tile / ntn) * 64;
        const int rr = tid >> 4, cc = (tid & 15) * 4;
#pragma unroll
        for (int u = 0; u < 4; ++u) {
            const float4 v = *(const float4*)(src + (size_t)(k0 + rr + u * 16) * N + n0 + cc);
            T[rr + u * 16][cc + 0] = v.x; T[rr + u * 16][cc + 1] = v.y;
            T[rr + u * 16][cc + 2] = v.z; T[rr + u * 16][cc + 3] = v.w;
        }
        __syncthreads();
#pragma unroll
        for (int u = 0; u < 4; ++u) {
            const int n = rr + u * 16;
            ushort4 o;
            o.x = f2bf(T[cc + 0][n]); o.y = f2bf(T[cc + 1][n]);
            o.z = f2bf(T[cc + 2][n]); o.w = f2bf(T[cc + 3][n]);
            *(ushort4*)(dst + (size_t)(n0 + n) * K + k0 + cc) = o;
        }
    } else if (blk < 3072 + 4096) {
        const int i = (blk - 3072) * 1024 + tid * 4;
        float4 v = *(const float4*)(x + i);
        ushort4 o = {f2bf(v.x), f2bf(v.y), f2bf(v.z), f2bf(v.w)};
        *(ushort4*)(xb + i) = o;
    } else {
#pragma unroll
        for (int u = 0; u < 12; ++u) {
            const int i = u * 256 + tid;
            bqkv[i] = i < 1024 ? bq[i] : (i < 2048 ? bk[i - 1024] : bv[i - 2048]);
        }
    }
}

// ---------------------------------------------------------------------------
extern "C" void kernel_launch(void* const* d_in, const int* in_sizes, int n_in,
                              void* d_out, int out_size, void* d_ws, size_t ws_size,
                              hipStream_t stream)
{
    (void)in_sizes; (void)n_in; (void)out_size; (void)ws_size;

    const float* x   = (const float*)d_in[0];
    const float* Wq  = (const float*)d_in[1];
    const float* bq  = (const float*)d_in[2];
    const float* Wk  = (const float*)d_in[3];
    const float* bk  = (const float*)d_in[4];
    const float* Wv  = (const float*)d_in[5];
    const float* bv  = (const float*)d_in[6];
    const float* Wm  = (const float*)d_in[7];
    const float* bm  = (const float*)d_in[8];
    const float* W1  = (const float*)d_in[9];
    const float* b1  = (const float*)d_in[10];
    const float* W2  = (const float*)d_in[11];
    const float* b2  = (const float*)d_in[12];
    const float* g1  = (const float*)d_in[13];
    const float* be1 = (const float*)d_in[14];
    const float* g2  = (const float*)d_in[15];
    const float* be2 = (const float*)d_in[16];
    float* out = (float*)d_out;

    char* base = (char*)d_ws;
    const size_t MB = 1u << 20;
    u16*   wqkv_t = (u16*)(base);              //  0..6MB : [3072][1024]
    u16*   wm_t   = (u16*)(base + 6 * MB);     //  6..8MB
    u16*   w1_t   = (u16*)(base + 8 * MB);     //  8..16MB: [4096][1024]
    u16*   w2_t   = (u16*)(base + 16 * MB);    // 16..24MB: [1024][4096]
    float* bqkv   = (float*)(base + 24 * MB);
    u16*   xb     = (u16*)(base + 25 * MB);    // 25..33MB (dead after QKV)
    u16*   qkv    = (u16*)(base + 33 * MB);    // 33..57MB [4096][3072]
    u16*   ao     = (u16*)(base + 57 * MB);    // 57..65MB
    u16*   f1     = (u16*)(base + 33 * MB);    // alias qkv+ao
    u16*   msg    = (u16*)(base + 25 * MB);    // alias xb
    u16*   ffn    = (u16*)(base + 25 * MB);
    float* hf     = (float*)(base + 65 * MB);
    u16*   hb     = (u16*)(base + 81 * MB);

    dim3 blk(256);
    prep<<<dim3(3072 + 4096 + 1), blk, 0, stream>>>(Wq, Wk, Wv, Wm, W1, W2, x,
                                                    bq, bk, bv,
                                                    wqkv_t, wm_t, w1_t, w2_t, xb, bqkv);

    gemm_pipe<0><<<dim3(12, 16), dim3(512), 0, stream>>>(xb, wqkv_t, bqkv, qkv, N_TOK, 3072, 1024);
    attn_mfma<<<dim3(SEQ_L / 128, 32), dim3(512), 0, stream>>>(qkv, ao);
    gemm_pipe128<0><<<dim3(8, 32), dim3(512), 0, stream>>>(ao, wm_t, bm, msg, N_TOK, 1024, 1024);
    add_ln<1><<<dim3(N_TOK), blk, 0, stream>>>(x, msg, g1, be1, hf, hb);
    gemm_pipe<1><<<dim3(16, 16), dim3(512), 0, stream>>>(hb, w1_t, b1, f1, N_TOK, FF_DIM, 1024);
    gemm_pipe128<0><<<dim3(8, 32), dim3(512), 0, stream>>>(f1, w2_t, b2, ffn, N_TOK, 1024, FF_DIM);
    add_ln<0><<<dim3(N_TOK), blk, 0, stream>>>(hf, ffn, g2, be2, out, nullptr);
}